// Round 1
// baseline (4527.287 us; speedup 1.0000x reference)
//
#include <hip/hip_runtime.h>
#include <math.h>

#define BB 8
#define SS 512
#define MM 512
#define TT 1024
#define DD 1024
#define HH 16
#define DH 64

// ---------------------------------------------------------------------------
// GEMM: C[m][n] = sum_k Arow(m)[k] * W[n][k]   (A [Mrows,1024], W [1024,1024])
// CONCAT=1: Arow(m) is h = concat(mem, x) along axis 1 (rows 0..511 = mem).
// 64x64 tile, BK=32, 256 threads, 4x4 per thread, fp32.
// ---------------------------------------------------------------------------
template <int CONCAT>
__global__ __launch_bounds__(256) void gemm_nt(const float* __restrict__ A,
                                               const float* __restrict__ A2,
                                               const float* __restrict__ W,
                                               float* __restrict__ C) {
  const int BK = 32;
  __shared__ float As[BK][68];  // k-major, stride 68 keeps 16B align + spreads banks
  __shared__ float Bs[BK][68];

  const int m0 = blockIdx.y * 64;
  const int n0 = blockIdx.x * 64;
  const int t = threadIdx.x;
  const int tx = t & 15;
  const int ty = t >> 4;

  float acc[4][4] = {};

  const int lrow = t >> 2;        // 0..63
  const int lk4 = (t & 3) * 4;    // 0,4,8,12

  // resolve A row pointer once (row fixed across k-tiles)
  const float* arow;
  {
    int gm = m0 + lrow;
    if (CONCAT) {
      int b = gm >> 10, tt = gm & 1023;
      arow = (tt < MM) ? (A + ((size_t)b * MM + tt) * DD)
                       : (A2 + ((size_t)b * SS + (tt - MM)) * DD);
    } else {
      arow = A + (size_t)gm * DD;
    }
  }
  const float* wrow = W + (size_t)(n0 + lrow) * DD;

  for (int k0 = 0; k0 < 1024; k0 += BK) {
#pragma unroll
    for (int half = 0; half < 2; ++half) {
      int kk = lk4 + half * 16;
      float4 a = *(const float4*)(arow + k0 + kk);
      As[kk + 0][lrow] = a.x; As[kk + 1][lrow] = a.y;
      As[kk + 2][lrow] = a.z; As[kk + 3][lrow] = a.w;
      float4 w = *(const float4*)(wrow + k0 + kk);
      Bs[kk + 0][lrow] = w.x; Bs[kk + 1][lrow] = w.y;
      Bs[kk + 2][lrow] = w.z; Bs[kk + 3][lrow] = w.w;
    }
    __syncthreads();
#pragma unroll
    for (int kk = 0; kk < BK; ++kk) {
      float4 a4 = *(const float4*)&As[kk][ty * 4];
      float4 b4 = *(const float4*)&Bs[kk][tx * 4];
      float av[4] = {a4.x, a4.y, a4.z, a4.w};
      float bv[4] = {b4.x, b4.y, b4.z, b4.w};
#pragma unroll
      for (int ii = 0; ii < 4; ++ii)
#pragma unroll
        for (int jj = 0; jj < 4; ++jj) acc[ii][jj] += av[ii] * bv[jj];
    }
    __syncthreads();
  }

#pragma unroll
  for (int ii = 0; ii < 4; ++ii) {
    float4 o = make_float4(acc[ii][0], acc[ii][1], acc[ii][2], acc[ii][3]);
    *(float4*)(C + (size_t)(m0 + ty * 4 + ii) * DD + n0 + tx * 4) = o;
  }
}

// ---------------------------------------------------------------------------
// Attention: one block per (b, h, i). Full row of scores (T=1024) in LDS,
// plain two-pass softmax, PV with LDS-staged v tiles.
// score(i,j) = ((q_i+u)·k_j + (q_i+t)·r_{j-i+S-1}) / 8   for j <= i+M
// note: for valid j the shift index never wraps mod T.
// att aliases q buffer: each block reads exactly the slice it later writes.
// ---------------------------------------------------------------------------
__global__ __launch_bounds__(256) void attn_row(const float* q, const float* __restrict__ k,
                                                const float* __restrict__ v,
                                                const float* __restrict__ r,
                                                const float* __restrict__ u,
                                                const float* __restrict__ tvec, float* att) {
  const int bh = blockIdx.y;  // 0..127
  const int b = bh >> 4, h = bh & 15;
  const int i = blockIdx.x;  // 0..511
  const int t = threadIdx.x;
  const int lane = t & 63;
  const int w = t >> 6;

  __shared__ float qu[DH], qt[DH];
  __shared__ float sc[TT];
  __shared__ float vs[64][DH + 4];
  __shared__ float red[8];

  if (t < DH) {
    float qv = q[((size_t)b * SS + i) * DD + h * DH + t];
    qu[t] = qv + u[h * DH + t];
    qt[t] = qv + tvec[h * DH + t];
  }
  __syncthreads();

  const int jmax = i + MM;  // inclusive

  // ---- scores ----
  for (int j = t; j < TT; j += 256) {
    float s;
    if (j <= jmax) {
      const float* krow = k + ((size_t)b * TT + j) * DD + h * DH;
      const float* rrow = r + (size_t)(j - i + SS - 1) * DD + h * DH;
      float acc0 = 0.f, acc1 = 0.f;
#pragma unroll
      for (int d4 = 0; d4 < DH; d4 += 4) {
        float4 k4 = *(const float4*)(krow + d4);
        float4 r4 = *(const float4*)(rrow + d4);
        float4 q4 = *(const float4*)(&qu[d4]);
        float4 p4 = *(const float4*)(&qt[d4]);
        acc0 += q4.x * k4.x + q4.y * k4.y + q4.z * k4.z + q4.w * k4.w;
        acc1 += p4.x * r4.x + p4.y * r4.y + p4.z * r4.z + p4.w * r4.w;
      }
      s = (acc0 + acc1) * 0.125f;
    } else {
      s = -INFINITY;
    }
    sc[j] = s;
  }
  __syncthreads();

  // ---- softmax ----
  float lmax = -INFINITY;
  for (int j = t; j < TT; j += 256) lmax = fmaxf(lmax, sc[j]);
#pragma unroll
  for (int off = 32; off; off >>= 1) lmax = fmaxf(lmax, __shfl_xor(lmax, off));
  if (lane == 0) red[w] = lmax;
  __syncthreads();
  const float rowmax = fmaxf(fmaxf(red[0], red[1]), fmaxf(red[2], red[3]));

  float lsum = 0.f;
  for (int j = t; j < TT; j += 256) {
    float p = (j <= jmax) ? __expf(sc[j] - rowmax) : 0.f;
    sc[j] = p;
    lsum += p;
  }
#pragma unroll
  for (int off = 32; off; off >>= 1) lsum += __shfl_xor(lsum, off);
  if (lane == 0) red[4 + w] = lsum;
  __syncthreads();
  const float inv = 1.f / (red[4] + red[5] + red[6] + red[7]);

  // ---- PV ----
  float acc = 0.f;
  const int jj = t >> 6, d = t & 63;
  const int vr = t >> 2;            // staging row 0..63
  const int vc = (t & 3) * 16;      // staging col base
  for (int j0 = 0; j0 < TT; j0 += 64) {
    if (j0 > jmax) break;
    __syncthreads();  // protect vs against previous iteration's readers
    const float* vrow = v + ((size_t)b * TT + j0 + vr) * DD + h * DH + vc;
#pragma unroll
    for (int c = 0; c < 16; c += 4) {
      float4 vv = *(const float4*)(vrow + c);
      *(float4*)&vs[vr][vc + c] = vv;
    }
    __syncthreads();
#pragma unroll
    for (int jx = jj * 16; jx < jj * 16 + 16; ++jx) {
      acc += sc[j0 + jx] * vs[jx][d];
    }
  }
  __syncthreads();                   // all PV reads of sc done
  sc[jj * 64 + d] = acc;             // reuse sc as scratch
  __syncthreads();
  if (t < DH) {
    float o = (sc[t] + sc[64 + t] + sc[128 + t] + sc[192 + t]) * inv;
    att[((size_t)b * SS + i) * DD + h * DH + t] = o;
  }
}

// ---------------------------------------------------------------------------
// LayerNorm: y = out_pre + x; (y - mu)/sqrt(var+eps)*gamma + beta. One block/row.
// ---------------------------------------------------------------------------
__global__ __launch_bounds__(256) void ln_kernel(const float* __restrict__ ypre,
                                                 const float* __restrict__ x,
                                                 const float* __restrict__ gamma,
                                                 const float* __restrict__ beta,
                                                 float* __restrict__ out) {
  const int row = blockIdx.x;
  const int t = threadIdx.x;
  const int lane = t & 63, w = t >> 6;
  const float* yr = ypre + (size_t)row * DD;
  const float* xr = x + (size_t)row * DD;

  float4 yv = *(const float4*)(yr + t * 4);
  float4 xv = *(const float4*)(xr + t * 4);
  float v0 = yv.x + xv.x, v1 = yv.y + xv.y, v2 = yv.z + xv.z, v3 = yv.w + xv.w;

  float s = v0 + v1 + v2 + v3;
  float ss = v0 * v0 + v1 * v1 + v2 * v2 + v3 * v3;
  __shared__ float rs[4], rss[4];
#pragma unroll
  for (int off = 32; off; off >>= 1) {
    s += __shfl_xor(s, off);
    ss += __shfl_xor(ss, off);
  }
  if (!lane) { rs[w] = s; rss[w] = ss; }
  __syncthreads();
  s = rs[0] + rs[1] + rs[2] + rs[3];
  ss = rss[0] + rss[1] + rss[2] + rss[3];
  const float mu = s * (1.f / DD);
  const float var = ss * (1.f / DD) - mu * mu;
  const float rstd = rsqrtf(var + 1e-5f);

  float4 g = *(const float4*)(gamma + t * 4);
  float4 be = *(const float4*)(beta + t * 4);
  float4 o;
  o.x = (v0 - mu) * rstd * g.x + be.x;
  o.y = (v1 - mu) * rstd * g.y + be.y;
  o.z = (v2 - mu) * rstd * g.z + be.z;
  o.w = (v3 - mu) * rstd * g.w + be.w;
  *(float4*)(out + (size_t)row * DD + t * 4) = o;
}

// ---------------------------------------------------------------------------
extern "C" void kernel_launch(void* const* d_in, const int* in_sizes, int n_in,
                              void* d_out, int out_size, void* d_ws, size_t ws_size,
                              hipStream_t stream) {
  const float* x = (const float*)d_in[0];
  const float* mem = (const float*)d_in[1];
  const float* R = (const float*)d_in[2];
  const float* u = (const float*)d_in[3];
  const float* tv = (const float*)d_in[4];
  const float* Wq = (const float*)d_in[5];
  const float* Wk = (const float*)d_in[6];
  const float* Wv = (const float*)d_in[7];
  const float* Wr = (const float*)d_in[8];
  const float* Wo = (const float*)d_in[9];
  const float* gamma = (const float*)d_in[10];
  const float* beta = (const float*)d_in[11];
  float* out = (float*)d_out;

  float* q_ws = (float*)d_ws;                        // B*S*D = 4M floats (also att)
  float* k_ws = q_ws + (size_t)BB * SS * DD;         // B*T*D = 8M floats (also y_pre)
  float* v_ws = k_ws + (size_t)BB * TT * DD;         // 8M floats
  float* r_ws = v_ws + (size_t)BB * TT * DD;         // T*D = 1M floats

  dim3 blk(256);

  gemm_nt<0><<<dim3(16, (BB * SS) / 64), blk, 0, stream>>>(x, nullptr, Wq, q_ws);
  gemm_nt<1><<<dim3(16, (BB * TT) / 64), blk, 0, stream>>>(mem, x, Wk, k_ws);
  gemm_nt<1><<<dim3(16, (BB * TT) / 64), blk, 0, stream>>>(mem, x, Wv, v_ws);
  gemm_nt<0><<<dim3(16, TT / 64), blk, 0, stream>>>(R, nullptr, Wr, r_ws);

  attn_row<<<dim3(SS, BB * HH), blk, 0, stream>>>(q_ws, k_ws, v_ws, r_ws, u, tv, q_ws);

  float* ypre = k_ws;  // k dead after attention
  gemm_nt<0><<<dim3(16, (BB * SS) / 64), blk, 0, stream>>>(q_ws, nullptr, Wo, ypre);

  ln_kernel<<<dim3(BB * SS), blk, 0, stream>>>(ypre, x, gamma, beta, out);
}

// Round 2
// 927.437 us; speedup vs baseline: 4.8815x; 4.8815x over previous
//
#include <hip/hip_runtime.h>
#include <math.h>

#define BB 8
#define SS 512
#define MM 512
#define TT 1024
#define DD 1024
#define HH 16
#define DH 64

typedef __attribute__((ext_vector_type(8))) short bf16x8;
typedef __attribute__((ext_vector_type(4))) float f32x4;

__device__ inline ushort f2bf(float f) {
  union { float f; unsigned u; } x; x.f = f;
  unsigned r = x.u + 0x7fffu + ((x.u >> 16) & 1u);
  return (ushort)(r >> 16);
}

// ---------------------------------------------------------------------------
// GEMM: C[m][n] = sum_k Arow(m)[k] * W[n][k]. fp32 compute.
// CONCAT=1: Arow(m) = concat(mem, x) along rows.
// MODE 0: store fp32 to C0. MODE 1: store bf16 to C0.
// MODE 2: store bf16(acc + u[n]) to C0 and bf16(acc + t[n]) to C1.
// ---------------------------------------------------------------------------
template <int CONCAT, int MODE>
__global__ __launch_bounds__(256) void gemm_nt(const float* __restrict__ A,
                                               const float* __restrict__ A2,
                                               const float* __restrict__ W,
                                               float* __restrict__ C0f,
                                               ushort* __restrict__ C0b,
                                               ushort* __restrict__ C1b,
                                               const float* __restrict__ uvec,
                                               const float* __restrict__ tvec) {
  const int BK = 32;
  __shared__ float As[BK][68];
  __shared__ float Bs[BK][68];

  const int m0 = blockIdx.y * 64;
  const int n0 = blockIdx.x * 64;
  const int t = threadIdx.x;
  const int tx = t & 15;
  const int ty = t >> 4;

  float acc[4][4] = {};

  const int lrow = t >> 2;
  const int lk4 = (t & 3) * 4;

  const float* arow;
  {
    int gm = m0 + lrow;
    if (CONCAT) {
      int b = gm >> 10, tt = gm & 1023;
      arow = (tt < MM) ? (A + ((size_t)b * MM + tt) * DD)
                       : (A2 + ((size_t)b * SS + (tt - MM)) * DD);
    } else {
      arow = A + (size_t)gm * DD;
    }
  }
  const float* wrow = W + (size_t)(n0 + lrow) * DD;

  for (int k0 = 0; k0 < 1024; k0 += BK) {
#pragma unroll
    for (int half = 0; half < 2; ++half) {
      int kk = lk4 + half * 16;
      float4 a = *(const float4*)(arow + k0 + kk);
      As[kk + 0][lrow] = a.x; As[kk + 1][lrow] = a.y;
      As[kk + 2][lrow] = a.z; As[kk + 3][lrow] = a.w;
      float4 w = *(const float4*)(wrow + k0 + kk);
      Bs[kk + 0][lrow] = w.x; Bs[kk + 1][lrow] = w.y;
      Bs[kk + 2][lrow] = w.z; Bs[kk + 3][lrow] = w.w;
    }
    __syncthreads();
#pragma unroll
    for (int kk = 0; kk < BK; ++kk) {
      float4 a4 = *(const float4*)&As[kk][ty * 4];
      float4 b4 = *(const float4*)&Bs[kk][tx * 4];
      float av[4] = {a4.x, a4.y, a4.z, a4.w};
      float bv[4] = {b4.x, b4.y, b4.z, b4.w};
#pragma unroll
      for (int ii = 0; ii < 4; ++ii)
#pragma unroll
        for (int jj = 0; jj < 4; ++jj) acc[ii][jj] += av[ii] * bv[jj];
    }
    __syncthreads();
  }

  if (MODE == 0) {
#pragma unroll
    for (int ii = 0; ii < 4; ++ii) {
      float4 o = make_float4(acc[ii][0], acc[ii][1], acc[ii][2], acc[ii][3]);
      *(float4*)(C0f + (size_t)(m0 + ty * 4 + ii) * DD + n0 + tx * 4) = o;
    }
  } else if (MODE == 1) {
#pragma unroll
    for (int ii = 0; ii < 4; ++ii) {
      ushort4 o;
      o.x = f2bf(acc[ii][0]); o.y = f2bf(acc[ii][1]);
      o.z = f2bf(acc[ii][2]); o.w = f2bf(acc[ii][3]);
      *(ushort4*)(C0b + (size_t)(m0 + ty * 4 + ii) * DD + n0 + tx * 4) = o;
    }
  } else {
    float4 uv = *(const float4*)(uvec + n0 + tx * 4);
    float4 tv = *(const float4*)(tvec + n0 + tx * 4);
#pragma unroll
    for (int ii = 0; ii < 4; ++ii) {
      ushort4 o, p;
      o.x = f2bf(acc[ii][0] + uv.x); o.y = f2bf(acc[ii][1] + uv.y);
      o.z = f2bf(acc[ii][2] + uv.z); o.w = f2bf(acc[ii][3] + uv.w);
      p.x = f2bf(acc[ii][0] + tv.x); p.y = f2bf(acc[ii][1] + tv.y);
      p.z = f2bf(acc[ii][2] + tv.z); p.w = f2bf(acc[ii][3] + tv.w);
      *(ushort4*)(C0b + (size_t)(m0 + ty * 4 + ii) * DD + n0 + tx * 4) = o;
      *(ushort4*)(C1b + (size_t)(m0 + ty * 4 + ii) * DD + n0 + tx * 4) = p;
    }
  }
}

// ---------------------------------------------------------------------------
// MFMA flash attention. Block = 4 waves, handles (b, h, 64 q-rows).
// Wave w owns q rows [i0+16w, i0+16w+16). j-tiles of 64, online softmax.
// score(i,j) = (qu_i.k_j + qt_i.r_{j-i+511}) / 8 for j <= i+512 (no wrap in
// the valid region). bd via per-wave 16x96 MFMA strip + LDS gather.
// ---------------------------------------------------------------------------
__global__ __launch_bounds__(256) void attn_mfma(const ushort* __restrict__ qu,
                                                 const ushort* __restrict__ qt,
                                                 const ushort* __restrict__ kb,
                                                 const ushort* __restrict__ vb,
                                                 const ushort* __restrict__ rb,
                                                 float* __restrict__ att) {
  const int w = threadIdx.x >> 6;   // wave 0..3
  const int l = threadIdx.x & 63;
  const int m16 = l & 15;
  const int kg = l >> 4;            // 0..3
  const int bh = blockIdx.y;
  const int b = bh >> 4, h = bh & 15;
  const int i0 = blockIdx.x * 64;

  __shared__ ushort Vt[64][72];        // transposed V tile [d][j], padded
  __shared__ ushort plds[4][16][72];   // per-wave P tile [qrow][j], padded
  __shared__ float bds[4][16][96];     // per-wave bd strip [qrow][p-local]

  // A fragments: qu/qt rows for this wave (row = m16, k = kg*8 + b + 32*ks)
  bf16x8 aqu[2], aqt[2];
  {
    const ushort* qrow = qu + ((size_t)(b * SS + i0 + w * 16 + m16)) * DD + h * DH + kg * 8;
    aqu[0] = *(const bf16x8*)(const void*)(qrow);
    aqu[1] = *(const bf16x8*)(const void*)(qrow + 32);
    const ushort* qrow2 = qt + ((size_t)(b * SS + i0 + w * 16 + m16)) * DD + h * DH + kg * 8;
    aqt[0] = *(const bf16x8*)(const void*)(qrow2);
    aqt[1] = *(const bf16x8*)(const void*)(qrow2 + 32);
  }

  f32x4 O[4];
  float mrow[4], lrow[4];
#pragma unroll
  for (int nt = 0; nt < 4; ++nt) O[nt] = (f32x4){0.f, 0.f, 0.f, 0.f};
#pragma unroll
  for (int rg = 0; rg < 4; ++rg) { mrow[rg] = -1e30f; lrow[rg] = 0.f; }

  const int ntj = i0 / 64 + 9;  // j-tiles: j in [0, i0+576)
  for (int jt = 0; jt < ntj; ++jt) {
    const int j0 = jt * 64;

    __syncthreads();  // prev-iter PV readers done before Vt overwrite

    // ---- stage V tile transposed: Vt[d][j] ----
    {
      const int vr = threadIdx.x >> 2;         // j row 0..63
      const int vc = (threadIdx.x & 3) * 16;   // d base
      const ushort* vrow = vb + ((size_t)(b * TT + j0 + vr)) * DD + h * DH + vc;
      bf16x8 va = *(const bf16x8*)(const void*)(vrow);
      bf16x8 vb8 = *(const bf16x8*)(const void*)(vrow + 8);
#pragma unroll
      for (int e = 0; e < 8; ++e) {
        Vt[vc + e][vr] = ((const ushort*)&va)[e];
        Vt[vc + 8 + e][vr] = ((const ushort*)&vb8)[e];
      }
    }

    // ---- ac = qu . K^T (B frags direct from global) ----
    f32x4 ac[4];
#pragma unroll
    for (int nt = 0; nt < 4; ++nt) ac[nt] = (f32x4){0.f, 0.f, 0.f, 0.f};
#pragma unroll
    for (int nt = 0; nt < 4; ++nt) {
      const ushort* krow = kb + ((size_t)(b * TT + j0 + nt * 16 + m16)) * DD + h * DH + kg * 8;
#pragma unroll
      for (int ks = 0; ks < 2; ++ks) {
        bf16x8 bk = *(const bf16x8*)(const void*)(krow + ks * 32);
        ac[nt] = __builtin_amdgcn_mfma_f32_16x16x32_bf16(aqu[ks], bk, ac[nt], 0, 0, 0);
      }
    }

    // ---- bd strip: 16x96, p global = pb + f*16 + n ----
    {
      const int pb = j0 - i0 + 448 + (3 - w) * 16;
      f32x4 bd[6];
#pragma unroll
      for (int f = 0; f < 6; ++f) bd[f] = (f32x4){0.f, 0.f, 0.f, 0.f};
#pragma unroll
      for (int f = 0; f < 6; ++f) {
        int prow = pb + f * 16 + m16;
        if (prow > TT - 1) prow = TT - 1;  // clamped rows feed masked entries only
        const ushort* rrow = rb + (size_t)prow * DD + h * DH + kg * 8;
#pragma unroll
        for (int ks = 0; ks < 2; ++ks) {
          bf16x8 br = *(const bf16x8*)(const void*)(rrow + ks * 32);
          bd[f] = __builtin_amdgcn_mfma_f32_16x16x32_bf16(aqt[ks], br, bd[f], 0, 0, 0);
        }
      }
      // spill strip to LDS (C layout: row kg*4+rg, col f*16+m16)
#pragma unroll
      for (int f = 0; f < 6; ++f)
#pragma unroll
        for (int rg = 0; rg < 4; ++rg) bds[w][kg * 4 + rg][f * 16 + m16] = bd[f][rg];
    }

    // ---- gather bd, scale, mask ----
    float sc[4][4];
    float pmax[4];
#pragma unroll
    for (int rg = 0; rg < 4; ++rg) pmax[rg] = -1e30f;
#pragma unroll
    for (int nt = 0; nt < 4; ++nt) {
      const int jj = nt * 16 + m16;
      const int j = j0 + jj;
#pragma unroll
      for (int rg = 0; rg < 4; ++rg) {
        const int rw = kg * 4 + rg;
        float s = (ac[nt][rg] + bds[w][rw][jj + 15 - rw]) * 0.125f;
        const int iabs = i0 + w * 16 + rw;
        s = (j <= iabs + MM) ? s : -1e30f;
        sc[nt][rg] = s;
        pmax[rg] = fmaxf(pmax[rg], s);
      }
    }
    // row max across the 16-lane group
#pragma unroll
    for (int rg = 0; rg < 4; ++rg) {
#pragma unroll
      for (int off = 1; off < 16; off <<= 1) pmax[rg] = fmaxf(pmax[rg], __shfl_xor(pmax[rg], off));
    }

    // online rescale
    float psum[4] = {0.f, 0.f, 0.f, 0.f};
#pragma unroll
    for (int rg = 0; rg < 4; ++rg) {
      float mnew = fmaxf(mrow[rg], pmax[rg]);
      float scale = __expf(mrow[rg] - mnew);
      mrow[rg] = mnew;
      lrow[rg] *= scale;
#pragma unroll
      for (int nt = 0; nt < 4; ++nt) O[nt][rg] *= scale;
    }
    // p = exp(s - m), write bf16 to plds
#pragma unroll
    for (int nt = 0; nt < 4; ++nt) {
#pragma unroll
      for (int rg = 0; rg < 4; ++rg) {
        float p = __expf(sc[nt][rg] - mrow[rg]);
        psum[rg] += p;
        plds[w][kg * 4 + rg][nt * 16 + m16] = f2bf(p);
      }
    }
#pragma unroll
    for (int rg = 0; rg < 4; ++rg) {
#pragma unroll
      for (int off = 1; off < 16; off <<= 1) psum[rg] += __shfl_xor(psum[rg], off);
      lrow[rg] += psum[rg];
    }

    __syncthreads();  // Vt staged, plds written (plds is per-wave but cheap to share barrier)

    // ---- PV: O += P . V ----
#pragma unroll
    for (int ks = 0; ks < 2; ++ks) {
      bf16x8 pa = *(const bf16x8*)(const void*)&plds[w][m16][kg * 8 + ks * 32];
#pragma unroll
      for (int nt = 0; nt < 4; ++nt) {
        bf16x8 vf = *(const bf16x8*)(const void*)&Vt[nt * 16 + m16][kg * 8 + ks * 32];
        O[nt] = __builtin_amdgcn_mfma_f32_16x16x32_bf16(pa, vf, O[nt], 0, 0, 0);
      }
    }
  }

  // ---- epilogue ----
  float linv[4];
#pragma unroll
  for (int rg = 0; rg < 4; ++rg) linv[rg] = 1.f / lrow[rg];
#pragma unroll
  for (int nt = 0; nt < 4; ++nt) {
#pragma unroll
    for (int rg = 0; rg < 4; ++rg) {
      att[((size_t)(b * SS + i0 + w * 16 + kg * 4 + rg)) * DD + h * DH + nt * 16 + m16] =
          O[nt][rg] * linv[rg];
    }
  }
}

// ---------------------------------------------------------------------------
// LayerNorm over y = ypre + x.
// ---------------------------------------------------------------------------
__global__ __launch_bounds__(256) void ln_kernel(const float* __restrict__ ypre,
                                                 const float* __restrict__ x,
                                                 const float* __restrict__ gamma,
                                                 const float* __restrict__ beta,
                                                 float* __restrict__ out) {
  const int row = blockIdx.x;
  const int t = threadIdx.x;
  const int lane = t & 63, w = t >> 6;
  const float* yr = ypre + (size_t)row * DD;
  const float* xr = x + (size_t)row * DD;

  float4 yv = *(const float4*)(yr + t * 4);
  float4 xv = *(const float4*)(xr + t * 4);
  float v0 = yv.x + xv.x, v1 = yv.y + xv.y, v2 = yv.z + xv.z, v3 = yv.w + xv.w;

  float s = v0 + v1 + v2 + v3;
  float ss = v0 * v0 + v1 * v1 + v2 * v2 + v3 * v3;
  __shared__ float rs[4], rss[4];
#pragma unroll
  for (int off = 32; off; off >>= 1) {
    s += __shfl_xor(s, off);
    ss += __shfl_xor(ss, off);
  }
  if (!lane) { rs[w] = s; rss[w] = ss; }
  __syncthreads();
  s = rs[0] + rs[1] + rs[2] + rs[3];
  ss = rss[0] + rss[1] + rss[2] + rss[3];
  const float mu = s * (1.f / DD);
  const float var = ss * (1.f / DD) - mu * mu;
  const float rstd = rsqrtf(var + 1e-5f);

  float4 g = *(const float4*)(gamma + t * 4);
  float4 be = *(const float4*)(beta + t * 4);
  float4 o;
  o.x = (v0 - mu) * rstd * g.x + be.x;
  o.y = (v1 - mu) * rstd * g.y + be.y;
  o.z = (v2 - mu) * rstd * g.z + be.z;
  o.w = (v3 - mu) * rstd * g.w + be.w;
  *(float4*)(out + (size_t)row * DD + t * 4) = o;
}

// ---------------------------------------------------------------------------
extern "C" void kernel_launch(void* const* d_in, const int* in_sizes, int n_in,
                              void* d_out, int out_size, void* d_ws, size_t ws_size,
                              hipStream_t stream) {
  const float* x = (const float*)d_in[0];
  const float* mem = (const float*)d_in[1];
  const float* R = (const float*)d_in[2];
  const float* u = (const float*)d_in[3];
  const float* tv = (const float*)d_in[4];
  const float* Wq = (const float*)d_in[5];
  const float* Wk = (const float*)d_in[6];
  const float* Wv = (const float*)d_in[7];
  const float* Wr = (const float*)d_in[8];
  const float* Wo = (const float*)d_in[9];
  const float* gamma = (const float*)d_in[10];
  const float* beta = (const float*)d_in[11];
  float* out = (float*)d_out;

  // workspace layout (bytes): qu 8M, qt 8M, kb 16M, vb 16M, rb 2M, att 16M, ypre 16M = 82MB
  ushort* qu_b = (ushort*)d_ws;
  ushort* qt_b = qu_b + (size_t)BB * SS * DD;
  ushort* kb = qt_b + (size_t)BB * SS * DD;
  ushort* vb = kb + (size_t)BB * TT * DD;
  ushort* rb = vb + (size_t)BB * TT * DD;
  float* att = (float*)(rb + (size_t)TT * DD);
  float* ypre = att + (size_t)BB * SS * DD;

  dim3 blk(256);

  // projections (fp32 compute, bf16 store)
  gemm_nt<0, 2><<<dim3(16, (BB * SS) / 64), blk, 0, stream>>>(x, nullptr, Wq, nullptr, qu_b, qt_b, u, tv);
  gemm_nt<1, 1><<<dim3(16, (BB * TT) / 64), blk, 0, stream>>>(mem, x, Wk, nullptr, kb, nullptr, nullptr, nullptr);
  gemm_nt<1, 1><<<dim3(16, (BB * TT) / 64), blk, 0, stream>>>(mem, x, Wv, nullptr, vb, nullptr, nullptr, nullptr);
  gemm_nt<0, 1><<<dim3(16, TT / 64), blk, 0, stream>>>(R, nullptr, Wr, nullptr, rb, nullptr, nullptr, nullptr);

  attn_mfma<<<dim3(SS / 64, BB * HH), blk, 0, stream>>>(qu_b, qt_b, kb, vb, rb, att);

  gemm_nt<0, 0><<<dim3(16, (BB * SS) / 64), blk, 0, stream>>>(att, nullptr, Wo, ypre, nullptr, nullptr, nullptr, nullptr);

  ln_kernel<<<dim3(BB * SS), blk, 0, stream>>>(ypre, x, gamma, beta, out);
}

// Round 3
// 379.260 us; speedup vs baseline: 11.9372x; 2.4454x over previous
//
#include <hip/hip_runtime.h>
#include <math.h>

#define BB 8
#define SS 512
#define MM 512
#define TT 1024
#define DD 1024
#define HH 16
#define DH 64

typedef __attribute__((ext_vector_type(8))) short bf16x8;
typedef __attribute__((ext_vector_type(4))) float f32x4;

__device__ __forceinline__ ushort f2bf(float f) {
  union { float f; unsigned u; } x; x.f = f;
  unsigned r = x.u + 0x7fffu + ((x.u >> 16) & 1u);
  return (ushort)(r >> 16);
}

__device__ __forceinline__ void stage16(void* lds, const void* g) {
  __builtin_amdgcn_global_load_lds((const __attribute__((address_space(1))) void*)g,
                                   (__attribute__((address_space(3))) void*)lds, 16, 0, 0);
}

// ---------------------------------------------------------------------------
// fp32 -> bf16 cast, 8 elems/thread. dst_idx = i + (i>>19)*mult + add
// (mult/add implement the concat(mem,x) row interleave into hb).
// ---------------------------------------------------------------------------
__global__ __launch_bounds__(256) void cast_bf16(const float* __restrict__ src,
                                                 ushort* __restrict__ dst, int n,
                                                 int mult, int add) {
  int i = (blockIdx.x * 256 + threadIdx.x) * 8;
  if (i >= n) return;
  int b = i >> 19;
  size_t o = (size_t)i + (size_t)b * mult + add;
  float4 a = *(const float4*)(src + i);
  float4 c = *(const float4*)(src + i + 4);
  union { bf16x8 v; ushort u[8]; } pk;
  pk.u[0] = f2bf(a.x); pk.u[1] = f2bf(a.y); pk.u[2] = f2bf(a.z); pk.u[3] = f2bf(a.w);
  pk.u[4] = f2bf(c.x); pk.u[5] = f2bf(c.y); pk.u[6] = f2bf(c.z); pk.u[7] = f2bf(c.w);
  *(bf16x8*)(void*)(dst + o) = pk.v;
}

// ---------------------------------------------------------------------------
// MFMA GEMM: C[m][n] = sum_k A[m][k] * W[n][k], A/W bf16, fp32 accum.
// 128x128 tile, BK=32, 4 waves (2x2 of 64x64), global_load_lds staging (m97).
// ASEL 0: A row m -> A + m*DD.   ASEL 1: q-slice of hb: row m -> (b*T+M+s).
// MODE 0: fp32 out. MODE 1: bf16 out. MODE 2: bf16(acc+u[n]) and bf16(acc+t[n]).
// ---------------------------------------------------------------------------
template <int ASEL, int MODE>
__global__ __launch_bounds__(256) void gemm_bf16(const ushort* __restrict__ A,
                                                 const ushort* __restrict__ W,
                                                 float* __restrict__ Cf,
                                                 ushort* __restrict__ Cb,
                                                 ushort* __restrict__ C2b,
                                                 const float* __restrict__ uvec,
                                                 const float* __restrict__ tvec) {
  __shared__ ushort As[128 * 32];
  __shared__ ushort Bs[128 * 32];
  const int t = threadIdx.x;
  const int w = t >> 6, l = t & 63;
  const int m16 = l & 15, kg = l >> 4;
  const int m0 = blockIdx.y * 128, n0 = blockIdx.x * 128;
  const int wr = w >> 1, wc = w & 1;

  // staging chunk c (16B) -> row c>>2, col-chunk c&3; two chunks per thread
  const int c0 = t, c1 = t + 256;
  const ushort* asrc0;
  const ushort* asrc1;
  {
    int gm0 = m0 + (c0 >> 2), gm1 = m0 + (c1 >> 2);
    if (ASEL == 1) {
      asrc0 = A + ((size_t)((gm0 >> 9) * TT + MM + (gm0 & 511))) * DD + (c0 & 3) * 8;
      asrc1 = A + ((size_t)((gm1 >> 9) * TT + MM + (gm1 & 511))) * DD + (c1 & 3) * 8;
    } else {
      asrc0 = A + (size_t)gm0 * DD + (c0 & 3) * 8;
      asrc1 = A + (size_t)gm1 * DD + (c1 & 3) * 8;
    }
  }
  const ushort* bsrc0 = W + (size_t)(n0 + (c0 >> 2)) * DD + (c0 & 3) * 8;
  const ushort* bsrc1 = W + (size_t)(n0 + (c1 >> 2)) * DD + (c1 & 3) * 8;
  ushort* adst0 = As + c0 * 8;
  ushort* adst1 = As + c1 * 8;
  ushort* bdst0 = Bs + c0 * 8;
  ushort* bdst1 = Bs + c1 * 8;

  f32x4 acc[4][4];
#pragma unroll
  for (int mi = 0; mi < 4; ++mi)
#pragma unroll
    for (int ni = 0; ni < 4; ++ni) acc[mi][ni] = (f32x4){0.f, 0.f, 0.f, 0.f};

  for (int k0 = 0; k0 < DD; k0 += 32) {
    stage16(adst0, asrc0 + k0);
    stage16(adst1, asrc1 + k0);
    stage16(bdst0, bsrc0 + k0);
    stage16(bdst1, bsrc1 + k0);
    __syncthreads();
    bf16x8 af[4], bfr[4];
#pragma unroll
    for (int mi = 0; mi < 4; ++mi)
      af[mi] = *(const bf16x8*)(const void*)&As[(wr * 64 + mi * 16 + m16) * 32 + kg * 8];
#pragma unroll
    for (int ni = 0; ni < 4; ++ni)
      bfr[ni] = *(const bf16x8*)(const void*)&Bs[(wc * 64 + ni * 16 + m16) * 32 + kg * 8];
#pragma unroll
    for (int mi = 0; mi < 4; ++mi)
#pragma unroll
      for (int ni = 0; ni < 4; ++ni)
        acc[mi][ni] = __builtin_amdgcn_mfma_f32_16x16x32_bf16(af[mi], bfr[ni], acc[mi][ni], 0, 0, 0);
    __syncthreads();
  }

  const int rbase = m0 + wr * 64 + kg * 4;
  const int cbase = n0 + wc * 64 + m16;
  if (MODE == 0) {
#pragma unroll
    for (int mi = 0; mi < 4; ++mi)
#pragma unroll
      for (int ni = 0; ni < 4; ++ni)
#pragma unroll
        for (int rg = 0; rg < 4; ++rg)
          Cf[(size_t)(rbase + mi * 16 + rg) * DD + cbase + ni * 16] = acc[mi][ni][rg];
  } else if (MODE == 1) {
#pragma unroll
    for (int mi = 0; mi < 4; ++mi)
#pragma unroll
      for (int ni = 0; ni < 4; ++ni)
#pragma unroll
        for (int rg = 0; rg < 4; ++rg)
          Cb[(size_t)(rbase + mi * 16 + rg) * DD + cbase + ni * 16] = f2bf(acc[mi][ni][rg]);
  } else {
    float uv[4], tv[4];
#pragma unroll
    for (int ni = 0; ni < 4; ++ni) { uv[ni] = uvec[cbase + ni * 16]; tv[ni] = tvec[cbase + ni * 16]; }
#pragma unroll
    for (int mi = 0; mi < 4; ++mi)
#pragma unroll
      for (int ni = 0; ni < 4; ++ni)
#pragma unroll
        for (int rg = 0; rg < 4; ++rg) {
          size_t idx = (size_t)(rbase + mi * 16 + rg) * DD + cbase + ni * 16;
          Cb[idx] = f2bf(acc[mi][ni][rg] + uv[ni]);
          C2b[idx] = f2bf(acc[mi][ni][rg] + tv[ni]);
        }
  }
}

// ---------------------------------------------------------------------------
// MFMA flash attention (as round 2), bf16 output.
// ---------------------------------------------------------------------------
__global__ __launch_bounds__(256) void attn_mfma(const ushort* __restrict__ qu,
                                                 const ushort* __restrict__ qt,
                                                 const ushort* __restrict__ kb,
                                                 const ushort* __restrict__ vb,
                                                 const ushort* __restrict__ rb,
                                                 ushort* __restrict__ att) {
  const int w = threadIdx.x >> 6;
  const int l = threadIdx.x & 63;
  const int m16 = l & 15;
  const int kg = l >> 4;
  const int bh = blockIdx.y;
  const int b = bh >> 4, h = bh & 15;
  const int i0 = blockIdx.x * 64;

  __shared__ ushort Vt[64][72];
  __shared__ ushort plds[4][16][72];
  __shared__ float bds[4][16][96];

  bf16x8 aqu[2], aqt[2];
  {
    const ushort* qrow = qu + ((size_t)(b * SS + i0 + w * 16 + m16)) * DD + h * DH + kg * 8;
    aqu[0] = *(const bf16x8*)(const void*)(qrow);
    aqu[1] = *(const bf16x8*)(const void*)(qrow + 32);
    const ushort* qrow2 = qt + ((size_t)(b * SS + i0 + w * 16 + m16)) * DD + h * DH + kg * 8;
    aqt[0] = *(const bf16x8*)(const void*)(qrow2);
    aqt[1] = *(const bf16x8*)(const void*)(qrow2 + 32);
  }

  f32x4 O[4];
  float mrow[4], lrow[4];
#pragma unroll
  for (int nt = 0; nt < 4; ++nt) O[nt] = (f32x4){0.f, 0.f, 0.f, 0.f};
#pragma unroll
  for (int rg = 0; rg < 4; ++rg) { mrow[rg] = -1e30f; lrow[rg] = 0.f; }

  const int ntj = i0 / 64 + 9;
  for (int jt = 0; jt < ntj; ++jt) {
    const int j0 = jt * 64;

    __syncthreads();

    {
      const int vr = threadIdx.x >> 2;
      const int vc = (threadIdx.x & 3) * 16;
      const ushort* vrow = vb + ((size_t)(b * TT + j0 + vr)) * DD + h * DH + vc;
      bf16x8 va = *(const bf16x8*)(const void*)(vrow);
      bf16x8 vb8 = *(const bf16x8*)(const void*)(vrow + 8);
#pragma unroll
      for (int e = 0; e < 8; ++e) {
        Vt[vc + e][vr] = ((const ushort*)&va)[e];
        Vt[vc + 8 + e][vr] = ((const ushort*)&vb8)[e];
      }
    }

    f32x4 ac[4];
#pragma unroll
    for (int nt = 0; nt < 4; ++nt) ac[nt] = (f32x4){0.f, 0.f, 0.f, 0.f};
#pragma unroll
    for (int nt = 0; nt < 4; ++nt) {
      const ushort* krow = kb + ((size_t)(b * TT + j0 + nt * 16 + m16)) * DD + h * DH + kg * 8;
#pragma unroll
      for (int ks = 0; ks < 2; ++ks) {
        bf16x8 bk = *(const bf16x8*)(const void*)(krow + ks * 32);
        ac[nt] = __builtin_amdgcn_mfma_f32_16x16x32_bf16(aqu[ks], bk, ac[nt], 0, 0, 0);
      }
    }

    {
      const int pb = j0 - i0 + 448 + (3 - w) * 16;
      f32x4 bd[6];
#pragma unroll
      for (int f = 0; f < 6; ++f) bd[f] = (f32x4){0.f, 0.f, 0.f, 0.f};
#pragma unroll
      for (int f = 0; f < 6; ++f) {
        int prow = pb + f * 16 + m16;
        if (prow > TT - 1) prow = TT - 1;
        const ushort* rrow = rb + (size_t)prow * DD + h * DH + kg * 8;
#pragma unroll
        for (int ks = 0; ks < 2; ++ks) {
          bf16x8 br = *(const bf16x8*)(const void*)(rrow + ks * 32);
          bd[f] = __builtin_amdgcn_mfma_f32_16x16x32_bf16(aqt[ks], br, bd[f], 0, 0, 0);
        }
      }
#pragma unroll
      for (int f = 0; f < 6; ++f)
#pragma unroll
        for (int rg = 0; rg < 4; ++rg) bds[w][kg * 4 + rg][f * 16 + m16] = bd[f][rg];
    }

    float sc[4][4];
    float pmax[4];
#pragma unroll
    for (int rg = 0; rg < 4; ++rg) pmax[rg] = -1e30f;
#pragma unroll
    for (int nt = 0; nt < 4; ++nt) {
      const int jj = nt * 16 + m16;
      const int j = j0 + jj;
#pragma unroll
      for (int rg = 0; rg < 4; ++rg) {
        const int rw = kg * 4 + rg;
        float s = (ac[nt][rg] + bds[w][rw][jj + 15 - rw]) * 0.125f;
        const int iabs = i0 + w * 16 + rw;
        s = (j <= iabs + MM) ? s : -1e30f;
        sc[nt][rg] = s;
        pmax[rg] = fmaxf(pmax[rg], s);
      }
    }
#pragma unroll
    for (int rg = 0; rg < 4; ++rg) {
#pragma unroll
      for (int off = 1; off < 16; off <<= 1) pmax[rg] = fmaxf(pmax[rg], __shfl_xor(pmax[rg], off));
    }

    float psum[4] = {0.f, 0.f, 0.f, 0.f};
#pragma unroll
    for (int rg = 0; rg < 4; ++rg) {
      float mnew = fmaxf(mrow[rg], pmax[rg]);
      float scale = __expf(mrow[rg] - mnew);
      mrow[rg] = mnew;
      lrow[rg] *= scale;
#pragma unroll
      for (int nt = 0; nt < 4; ++nt) O[nt][rg] *= scale;
    }
#pragma unroll
    for (int nt = 0; nt < 4; ++nt) {
#pragma unroll
      for (int rg = 0; rg < 4; ++rg) {
        float p = __expf(sc[nt][rg] - mrow[rg]);
        psum[rg] += p;
        plds[w][kg * 4 + rg][nt * 16 + m16] = f2bf(p);
      }
    }
#pragma unroll
    for (int rg = 0; rg < 4; ++rg) {
#pragma unroll
      for (int off = 1; off < 16; off <<= 1) psum[rg] += __shfl_xor(psum[rg], off);
      lrow[rg] += psum[rg];
    }

    __syncthreads();

#pragma unroll
    for (int ks = 0; ks < 2; ++ks) {
      bf16x8 pa = *(const bf16x8*)(const void*)&plds[w][m16][kg * 8 + ks * 32];
#pragma unroll
      for (int nt = 0; nt < 4; ++nt) {
        bf16x8 vf = *(const bf16x8*)(const void*)&Vt[nt * 16 + m16][kg * 8 + ks * 32];
        O[nt] = __builtin_amdgcn_mfma_f32_16x16x32_bf16(pa, vf, O[nt], 0, 0, 0);
      }
    }
  }

  float linv[4];
#pragma unroll
  for (int rg = 0; rg < 4; ++rg) linv[rg] = 1.f / lrow[rg];
#pragma unroll
  for (int nt = 0; nt < 4; ++nt) {
#pragma unroll
    for (int rg = 0; rg < 4; ++rg) {
      att[((size_t)(b * SS + i0 + w * 16 + kg * 4 + rg)) * DD + h * DH + nt * 16 + m16] =
          f2bf(O[nt][rg] * linv[rg]);
    }
  }
}

// ---------------------------------------------------------------------------
// LayerNorm over y = ypre + x.
// ---------------------------------------------------------------------------
__global__ __launch_bounds__(256) void ln_kernel(const float* __restrict__ ypre,
                                                 const float* __restrict__ x,
                                                 const float* __restrict__ gamma,
                                                 const float* __restrict__ beta,
                                                 float* __restrict__ out) {
  const int row = blockIdx.x;
  const int t = threadIdx.x;
  const int lane = t & 63, w = t >> 6;
  const float* yr = ypre + (size_t)row * DD;
  const float* xr = x + (size_t)row * DD;

  float4 yv = *(const float4*)(yr + t * 4);
  float4 xv = *(const float4*)(xr + t * 4);
  float v0 = yv.x + xv.x, v1 = yv.y + xv.y, v2 = yv.z + xv.z, v3 = yv.w + xv.w;

  float s = v0 + v1 + v2 + v3;
  float ss = v0 * v0 + v1 * v1 + v2 * v2 + v3 * v3;
  __shared__ float rs[4], rss[4];
#pragma unroll
  for (int off = 32; off; off >>= 1) {
    s += __shfl_xor(s, off);
    ss += __shfl_xor(ss, off);
  }
  if (!lane) { rs[w] = s; rss[w] = ss; }
  __syncthreads();
  s = rs[0] + rs[1] + rs[2] + rs[3];
  ss = rss[0] + rss[1] + rss[2] + rss[3];
  const float mu = s * (1.f / DD);
  const float var = ss * (1.f / DD) - mu * mu;
  const float rstd = rsqrtf(var + 1e-5f);

  float4 g = *(const float4*)(gamma + t * 4);
  float4 be = *(const float4*)(beta + t * 4);
  float4 o;
  o.x = (v0 - mu) * rstd * g.x + be.x;
  o.y = (v1 - mu) * rstd * g.y + be.y;
  o.z = (v2 - mu) * rstd * g.z + be.z;
  o.w = (v3 - mu) * rstd * g.w + be.w;
  *(float4*)(out + (size_t)row * DD + t * 4) = o;
}

// ---------------------------------------------------------------------------
extern "C" void kernel_launch(void* const* d_in, const int* in_sizes, int n_in,
                              void* d_out, int out_size, void* d_ws, size_t ws_size,
                              hipStream_t stream) {
  const float* x = (const float*)d_in[0];
  const float* mem = (const float*)d_in[1];
  const float* R = (const float*)d_in[2];
  const float* u = (const float*)d_in[3];
  const float* tv = (const float*)d_in[4];
  const float* Wq = (const float*)d_in[5];
  const float* Wk = (const float*)d_in[6];
  const float* Wv = (const float*)d_in[7];
  const float* Wr = (const float*)d_in[8];
  const float* Wo = (const float*)d_in[9];
  const float* gamma = (const float*)d_in[10];
  const float* beta = (const float*)d_in[11];
  float* out = (float*)d_out;

  // ws layout (ushort units, 1M = 1<<20):
  ushort* hb = (ushort*)d_ws;                       // 8M  concat(mem,x) bf16
  ushort* Rb = hb + (8u << 20);                     // 1M
  ushort* Wqb = Rb + (1u << 20);                    // 1M
  ushort* Wkb = Wqb + (1u << 20);                   // 1M
  ushort* Wvb = Wkb + (1u << 20);                   // 1M
  ushort* Wrb = Wvb + (1u << 20);                   // 1M
  ushort* Wob = Wrb + (1u << 20);                   // 1M
  ushort* qu_b = Wob + (1u << 20);                  // 4M  (att aliases)
  ushort* qt_b = qu_b + (4u << 20);                 // 4M
  ushort* kb = qt_b + (4u << 20);                   // 8M  (ypre fp32 aliases)
  ushort* vb = kb + (8u << 20);                     // 8M
  ushort* rb = vb + (8u << 20);                     // 1M
  ushort* att = qu_b;
  float* ypre = (float*)kb;

  dim3 blk(256);
  const int NE_X = BB * SS * DD;   // 4M
  const int NE_W = DD * DD;        // 1M

  // casts
  cast_bf16<<<dim3(NE_X / 8 / 256), blk, 0, stream>>>(mem, hb, NE_X, 524288, 0);
  cast_bf16<<<dim3(NE_X / 8 / 256), blk, 0, stream>>>(x, hb, NE_X, 524288, 524288);
  cast_bf16<<<dim3(NE_W / 8 / 256), blk, 0, stream>>>(R, Rb, NE_W, 0, 0);
  cast_bf16<<<dim3(NE_W / 8 / 256), blk, 0, stream>>>(Wq, Wqb, NE_W, 0, 0);
  cast_bf16<<<dim3(NE_W / 8 / 256), blk, 0, stream>>>(Wk, Wkb, NE_W, 0, 0);
  cast_bf16<<<dim3(NE_W / 8 / 256), blk, 0, stream>>>(Wv, Wvb, NE_W, 0, 0);
  cast_bf16<<<dim3(NE_W / 8 / 256), blk, 0, stream>>>(Wr, Wrb, NE_W, 0, 0);
  cast_bf16<<<dim3(NE_W / 8 / 256), blk, 0, stream>>>(Wo, Wob, NE_W, 0, 0);

  // projections (bf16 MFMA)
  gemm_bf16<1, 2><<<dim3(8, 32), blk, 0, stream>>>(hb, Wqb, nullptr, qu_b, qt_b, u, tv);
  gemm_bf16<0, 1><<<dim3(8, 64), blk, 0, stream>>>(hb, Wkb, nullptr, kb, nullptr, nullptr, nullptr);
  gemm_bf16<0, 1><<<dim3(8, 64), blk, 0, stream>>>(hb, Wvb, nullptr, vb, nullptr, nullptr, nullptr);
  gemm_bf16<0, 1><<<dim3(8, 8), blk, 0, stream>>>(Rb, Wrb, nullptr, rb, nullptr, nullptr, nullptr);

  attn_mfma<<<dim3(SS / 64, BB * HH), blk, 0, stream>>>(qu_b, qt_b, kb, vb, rb, att);

  gemm_bf16<0, 0><<<dim3(8, 32), blk, 0, stream>>>(att, Wob, ypre, nullptr, nullptr, nullptr, nullptr);

  ln_kernel<<<dim3(BB * SS), blk, 0, stream>>>(ypre, x, gamma, beta, out);
}

// Round 4
// 366.774 us; speedup vs baseline: 12.3435x; 1.0340x over previous
//
#include <hip/hip_runtime.h>
#include <math.h>

#define BB 8
#define SS 512
#define MM 512
#define TT 1024
#define DD 1024
#define HH 16
#define DH 64

typedef __attribute__((ext_vector_type(8))) short bf16x8;
typedef __attribute__((ext_vector_type(4))) float f32x4;

__device__ __forceinline__ ushort f2bf(float f) {
  union { float f; unsigned u; } x; x.f = f;
  unsigned r = x.u + 0x7fffu + ((x.u >> 16) & 1u);
  return (ushort)(r >> 16);
}

__device__ __forceinline__ void stage16(void* lds, const void* g) {
  __builtin_amdgcn_global_load_lds((const __attribute__((address_space(1))) void*)g,
                                   (__attribute__((address_space(3))) void*)lds, 16, 0, 0);
}

// ---------------------------------------------------------------------------
// fp32 -> bf16 cast, 8 elems/thread. dst_idx = i + (i>>19)*mult + add
// (mult/add implement the concat(mem,x) row interleave into hb).
// ---------------------------------------------------------------------------
__global__ __launch_bounds__(256) void cast_bf16(const float* __restrict__ src,
                                                 ushort* __restrict__ dst, int n,
                                                 int mult, int add) {
  int i = (blockIdx.x * 256 + threadIdx.x) * 8;
  if (i >= n) return;
  int b = i >> 19;
  size_t o = (size_t)i + (size_t)b * mult + add;
  float4 a = *(const float4*)(src + i);
  float4 c = *(const float4*)(src + i + 4);
  union { bf16x8 v; ushort u[8]; } pk;
  pk.u[0] = f2bf(a.x); pk.u[1] = f2bf(a.y); pk.u[2] = f2bf(a.z); pk.u[3] = f2bf(a.w);
  pk.u[4] = f2bf(c.x); pk.u[5] = f2bf(c.y); pk.u[6] = f2bf(c.z); pk.u[7] = f2bf(c.w);
  *(bf16x8*)(void*)(dst + o) = pk.v;
}

// ---------------------------------------------------------------------------
// V transpose: vb[b][j][h*64+d] -> vt[(b*16+h)*64+d][j]  (bf16).
// One block per (b,h,64-j tile). Coalesced read, LDS transpose, coalesced write.
// ---------------------------------------------------------------------------
__global__ __launch_bounds__(256) void transp_v(const ushort* __restrict__ vb,
                                                ushort* __restrict__ vt) {
  const int b = blockIdx.y >> 4, h = blockIdx.y & 15;
  const int j0 = blockIdx.x * 64;
  const int t = threadIdx.x;
  __shared__ ushort tile[64][72];  // [d][j]
#pragma unroll
  for (int cc = 0; cc < 2; ++cc) {
    int c = t + cc * 256;
    int jrow = c >> 3, dcol = (c & 7) * 8;
    bf16x8 v = *(const bf16x8*)(const void*)(vb + ((size_t)(b * TT + j0 + jrow)) * DD + h * DH + dcol);
#pragma unroll
    for (int e = 0; e < 8; ++e) tile[dcol + e][jrow] = ((const ushort*)&v)[e];
  }
  __syncthreads();
#pragma unroll
  for (int cc = 0; cc < 2; ++cc) {
    int c = t + cc * 256;
    int d = c >> 3, jcol = (c & 7) * 8;
    bf16x8 o = *(const bf16x8*)(const void*)&tile[d][jcol];
    *(bf16x8*)(void*)(vt + ((size_t)((b * HH + h) * DH + d)) * TT + j0 + jcol) = o;
  }
}

// ---------------------------------------------------------------------------
// MFMA GEMM (m97 structure): C[m][n] = sum_k A[m][k] * W[n][k], bf16 in, fp32 acc.
// 128x128 tile, BK=32, 4 waves, global_load_lds staging.
// ASEL 1: A row m -> hb row (b*T + M + s) (q-slice of concat buffer).
// MODE 0: fp32 out. MODE 1: bf16 out. MODE 2: bf16(acc+u[n]) and bf16(acc+t[n]).
// ---------------------------------------------------------------------------
template <int ASEL, int MODE>
__global__ __launch_bounds__(256) void gemm_bf16(const ushort* __restrict__ A,
                                                 const ushort* __restrict__ W,
                                                 float* __restrict__ Cf,
                                                 ushort* __restrict__ Cb,
                                                 ushort* __restrict__ C2b,
                                                 const float* __restrict__ uvec,
                                                 const float* __restrict__ tvec) {
  __shared__ ushort As[128 * 32];
  __shared__ ushort Bs[128 * 32];
  const int t = threadIdx.x;
  const int w = t >> 6, l = t & 63;
  const int m16 = l & 15, kg = l >> 4;
  const int m0 = blockIdx.y * 128, n0 = blockIdx.x * 128;
  const int wr = w >> 1, wc = w & 1;

  const int c0 = t, c1 = t + 256;
  const ushort* asrc0;
  const ushort* asrc1;
  {
    int gm0 = m0 + (c0 >> 2), gm1 = m0 + (c1 >> 2);
    if (ASEL == 1) {
      asrc0 = A + ((size_t)((gm0 >> 9) * TT + MM + (gm0 & 511))) * DD + (c0 & 3) * 8;
      asrc1 = A + ((size_t)((gm1 >> 9) * TT + MM + (gm1 & 511))) * DD + (c1 & 3) * 8;
    } else {
      asrc0 = A + (size_t)gm0 * DD + (c0 & 3) * 8;
      asrc1 = A + (size_t)gm1 * DD + (c1 & 3) * 8;
    }
  }
  const ushort* bsrc0 = W + (size_t)(n0 + (c0 >> 2)) * DD + (c0 & 3) * 8;
  const ushort* bsrc1 = W + (size_t)(n0 + (c1 >> 2)) * DD + (c1 & 3) * 8;
  ushort* adst0 = As + c0 * 8;
  ushort* adst1 = As + c1 * 8;
  ushort* bdst0 = Bs + c0 * 8;
  ushort* bdst1 = Bs + c1 * 8;

  f32x4 acc[4][4];
#pragma unroll
  for (int mi = 0; mi < 4; ++mi)
#pragma unroll
    for (int ni = 0; ni < 4; ++ni) acc[mi][ni] = (f32x4){0.f, 0.f, 0.f, 0.f};

  for (int k0 = 0; k0 < DD; k0 += 32) {
    stage16(adst0, asrc0 + k0);
    stage16(adst1, asrc1 + k0);
    stage16(bdst0, bsrc0 + k0);
    stage16(bdst1, bsrc1 + k0);
    __syncthreads();
    bf16x8 af[4], bfr[4];
#pragma unroll
    for (int mi = 0; mi < 4; ++mi)
      af[mi] = *(const bf16x8*)(const void*)&As[(wr * 64 + mi * 16 + m16) * 32 + kg * 8];
#pragma unroll
    for (int ni = 0; ni < 4; ++ni)
      bfr[ni] = *(const bf16x8*)(const void*)&Bs[(wc * 64 + ni * 16 + m16) * 32 + kg * 8];
#pragma unroll
    for (int mi = 0; mi < 4; ++mi)
#pragma unroll
      for (int ni = 0; ni < 4; ++ni)
        acc[mi][ni] = __builtin_amdgcn_mfma_f32_16x16x32_bf16(af[mi], bfr[ni], acc[mi][ni], 0, 0, 0);
    __syncthreads();
  }

  const int rbase = m0 + wr * 64 + kg * 4;
  const int cbase = n0 + wc * 64 + m16;
  if (MODE == 0) {
#pragma unroll
    for (int mi = 0; mi < 4; ++mi)
#pragma unroll
      for (int ni = 0; ni < 4; ++ni)
#pragma unroll
        for (int rg = 0; rg < 4; ++rg)
          Cf[(size_t)(rbase + mi * 16 + rg) * DD + cbase + ni * 16] = acc[mi][ni][rg];
  } else if (MODE == 1) {
#pragma unroll
    for (int mi = 0; mi < 4; ++mi)
#pragma unroll
      for (int ni = 0; ni < 4; ++ni)
#pragma unroll
        for (int rg = 0; rg < 4; ++rg)
          Cb[(size_t)(rbase + mi * 16 + rg) * DD + cbase + ni * 16] = f2bf(acc[mi][ni][rg]);
  } else {
    float uv[4], tv[4];
#pragma unroll
    for (int ni = 0; ni < 4; ++ni) { uv[ni] = uvec[cbase + ni * 16]; tv[ni] = tvec[cbase + ni * 16]; }
#pragma unroll
    for (int mi = 0; mi < 4; ++mi)
#pragma unroll
      for (int ni = 0; ni < 4; ++ni)
#pragma unroll
        for (int rg = 0; rg < 4; ++rg) {
          size_t idx = (size_t)(rbase + mi * 16 + rg) * DD + cbase + ni * 16;
          Cb[idx] = f2bf(acc[mi][ni][rg] + uv[ni]);
          C2b[idx] = f2bf(acc[mi][ni][rg] + tv[ni]);
        }
  }
}

// ---------------------------------------------------------------------------
// MFMA flash attention, barrier-free. Block = 4 independent waves; wave w owns
// q rows [i0+16w, i0+16w+16). plds/bds are wave-private. V read pre-transposed
// from global. Defer-max with THR=8.
// ---------------------------------------------------------------------------
__global__ __launch_bounds__(256) void attn_mfma(const ushort* __restrict__ qu,
                                                 const ushort* __restrict__ qt,
                                                 const ushort* __restrict__ kb,
                                                 const ushort* __restrict__ vt,
                                                 const ushort* __restrict__ rb,
                                                 ushort* __restrict__ att) {
  const int w = threadIdx.x >> 6;
  const int l = threadIdx.x & 63;
  const int m16 = l & 15;
  const int kg = l >> 4;
  const int bh = blockIdx.y;
  const int b = bh >> 4, h = bh & 15;
  const int i0 = blockIdx.x * 64;

  __shared__ ushort plds[4][16][72];  // per-wave P tile [q][j]
  __shared__ float bds[4][16][84];    // per-wave bd strip [q][p-offset], 80 used

  bf16x8 aqu[2], aqt[2];
  {
    const ushort* qrow = qu + ((size_t)(b * SS + i0 + w * 16 + m16)) * DD + h * DH + kg * 8;
    aqu[0] = *(const bf16x8*)(const void*)(qrow);
    aqu[1] = *(const bf16x8*)(const void*)(qrow + 32);
    const ushort* qrow2 = qt + ((size_t)(b * SS + i0 + w * 16 + m16)) * DD + h * DH + kg * 8;
    aqt[0] = *(const bf16x8*)(const void*)(qrow2);
    aqt[1] = *(const bf16x8*)(const void*)(qrow2 + 32);
  }

  const ushort* vbase = vt + ((size_t)(b * HH + h)) * DH * TT;

  f32x4 O[4];
  float mrow[4], lrow[4];
#pragma unroll
  for (int nt = 0; nt < 4; ++nt) O[nt] = (f32x4){0.f, 0.f, 0.f, 0.f};
#pragma unroll
  for (int rg = 0; rg < 4; ++rg) { mrow[rg] = -1e30f; lrow[rg] = 0.f; }

  const int ntj = i0 / 64 + 9;
  for (int jt = 0; jt < ntj; ++jt) {
    const int j0 = jt * 64;

    // ---- ac = qu . K^T ----
    f32x4 ac[4];
#pragma unroll
    for (int nt = 0; nt < 4; ++nt) ac[nt] = (f32x4){0.f, 0.f, 0.f, 0.f};
#pragma unroll
    for (int nt = 0; nt < 4; ++nt) {
      const ushort* krow = kb + ((size_t)(b * TT + j0 + nt * 16 + m16)) * DD + h * DH + kg * 8;
#pragma unroll
      for (int ks = 0; ks < 2; ++ks) {
        bf16x8 bk = *(const bf16x8*)(const void*)(krow + ks * 32);
        ac[nt] = __builtin_amdgcn_mfma_f32_16x16x32_bf16(aqu[ks], bk, ac[nt], 0, 0, 0);
      }
    }

    // ---- bd strip: 16x80, p-offset 0..79 covers needed 0..78 ----
    {
      const int pb = j0 - i0 - w * 16 + 496;
      f32x4 bd[5];
#pragma unroll
      for (int f = 0; f < 5; ++f) bd[f] = (f32x4){0.f, 0.f, 0.f, 0.f};
#pragma unroll
      for (int f = 0; f < 5; ++f) {
        int prow = pb + f * 16 + m16;
        if (prow > TT - 1) prow = TT - 1;  // clamped rows feed masked entries only
        const ushort* rrow = rb + (size_t)prow * DD + h * DH + kg * 8;
#pragma unroll
        for (int ks = 0; ks < 2; ++ks) {
          bf16x8 br = *(const bf16x8*)(const void*)(rrow + ks * 32);
          bd[f] = __builtin_amdgcn_mfma_f32_16x16x32_bf16(aqt[ks], br, bd[f], 0, 0, 0);
        }
      }
#pragma unroll
      for (int f = 0; f < 5; ++f)
#pragma unroll
        for (int rg = 0; rg < 4; ++rg) bds[w][kg * 4 + rg][f * 16 + m16] = bd[f][rg];
    }

    // ---- gather bd, scale, mask (within-wave LDS dep; no barrier needed) ----
    float sc[4][4];
    float pmax[4];
#pragma unroll
    for (int rg = 0; rg < 4; ++rg) pmax[rg] = -1e30f;
#pragma unroll
    for (int nt = 0; nt < 4; ++nt) {
      const int jj = nt * 16 + m16;
      const int j = j0 + jj;
#pragma unroll
      for (int rg = 0; rg < 4; ++rg) {
        const int rw = kg * 4 + rg;
        float s = (ac[nt][rg] + bds[w][rw][jj + 15 - rw]) * 0.125f;
        const int iabs = i0 + w * 16 + rw;
        s = (j <= iabs + MM) ? s : -1e30f;
        sc[nt][rg] = s;
        pmax[rg] = fmaxf(pmax[rg], s);
      }
    }
#pragma unroll
    for (int rg = 0; rg < 4; ++rg) {
#pragma unroll
      for (int off = 1; off < 16; off <<= 1) pmax[rg] = fmaxf(pmax[rg], __shfl_xor(pmax[rg], off));
    }

    // ---- defer-max rescale (THR=8) ----
    bool grow = false;
#pragma unroll
    for (int rg = 0; rg < 4; ++rg) grow = grow || (pmax[rg] > mrow[rg] + 8.f);
    if (__any(grow)) {
#pragma unroll
      for (int rg = 0; rg < 4; ++rg) {
        float mnew = fmaxf(mrow[rg], pmax[rg]);
        float scale = __expf(mrow[rg] - mnew);
        mrow[rg] = mnew;
        lrow[rg] *= scale;
#pragma unroll
        for (int nt = 0; nt < 4; ++nt) O[nt][rg] *= scale;
      }
    }

    float psum[4] = {0.f, 0.f, 0.f, 0.f};
#pragma unroll
    for (int nt = 0; nt < 4; ++nt) {
#pragma unroll
      for (int rg = 0; rg < 4; ++rg) {
        float p = __expf(sc[nt][rg] - mrow[rg]);
        psum[rg] += p;
        plds[w][kg * 4 + rg][nt * 16 + m16] = f2bf(p);
      }
    }
#pragma unroll
    for (int rg = 0; rg < 4; ++rg) {
#pragma unroll
      for (int off = 1; off < 16; off <<= 1) psum[rg] += __shfl_xor(psum[rg], off);
      lrow[rg] += psum[rg];
    }

    // ---- PV: O += P . V (V^T fragments direct from global) ----
#pragma unroll
    for (int ks = 0; ks < 2; ++ks) {
      bf16x8 pa = *(const bf16x8*)(const void*)&plds[w][m16][kg * 8 + ks * 32];
#pragma unroll
      for (int nt = 0; nt < 4; ++nt) {
        bf16x8 vf = *(const bf16x8*)(const void*)(vbase + (size_t)(nt * 16 + m16) * TT + j0 + ks * 32 + kg * 8);
        O[nt] = __builtin_amdgcn_mfma_f32_16x16x32_bf16(pa, vf, O[nt], 0, 0, 0);
      }
    }
  }

  float linv[4];
#pragma unroll
  for (int rg = 0; rg < 4; ++rg) linv[rg] = 1.f / lrow[rg];
#pragma unroll
  for (int nt = 0; nt < 4; ++nt) {
#pragma unroll
    for (int rg = 0; rg < 4; ++rg) {
      att[((size_t)(b * SS + i0 + w * 16 + kg * 4 + rg)) * DD + h * DH + nt * 16 + m16] =
          f2bf(O[nt][rg] * linv[rg]);
    }
  }
}

// ---------------------------------------------------------------------------
// LayerNorm over y = ypre + x.
// ---------------------------------------------------------------------------
__global__ __launch_bounds__(256) void ln_kernel(const float* __restrict__ ypre,
                                                 const float* __restrict__ x,
                                                 const float* __restrict__ gamma,
                                                 const float* __restrict__ beta,
                                                 float* __restrict__ out) {
  const int row = blockIdx.x;
  const int t = threadIdx.x;
  const int lane = t & 63, w = t >> 6;
  const float* yr = ypre + (size_t)row * DD;
  const float* xr = x + (size_t)row * DD;

  float4 yv = *(const float4*)(yr + t * 4);
  float4 xv = *(const float4*)(xr + t * 4);
  float v0 = yv.x + xv.x, v1 = yv.y + xv.y, v2 = yv.z + xv.z, v3 = yv.w + xv.w;

  float s = v0 + v1 + v2 + v3;
  float ss = v0 * v0 + v1 * v1 + v2 * v2 + v3 * v3;
  __shared__ float rs[4], rss[4];
#pragma unroll
  for (int off = 32; off; off >>= 1) {
    s += __shfl_xor(s, off);
    ss += __shfl_xor(ss, off);
  }
  if (!lane) { rs[w] = s; rss[w] = ss; }
  __syncthreads();
  s = rs[0] + rs[1] + rs[2] + rs[3];
  ss = rss[0] + rss[1] + rss[2] + rss[3];
  const float mu = s * (1.f / DD);
  const float var = ss * (1.f / DD) - mu * mu;
  const float rstd = rsqrtf(var + 1e-5f);

  float4 g = *(const float4*)(gamma + t * 4);
  float4 be = *(const float4*)(beta + t * 4);
  float4 o;
  o.x = (v0 - mu) * rstd * g.x + be.x;
  o.y = (v1 - mu) * rstd * g.y + be.y;
  o.z = (v2 - mu) * rstd * g.z + be.z;
  o.w = (v3 - mu) * rstd * g.w + be.w;
  *(float4*)(out + (size_t)row * DD + t * 4) = o;
}

// ---------------------------------------------------------------------------
extern "C" void kernel_launch(void* const* d_in, const int* in_sizes, int n_in,
                              void* d_out, int out_size, void* d_ws, size_t ws_size,
                              hipStream_t stream) {
  const float* x = (const float*)d_in[0];
  const float* mem = (const float*)d_in[1];
  const float* R = (const float*)d_in[2];
  const float* u = (const float*)d_in[3];
  const float* tv = (const float*)d_in[4];
  const float* Wq = (const float*)d_in[5];
  const float* Wk = (const float*)d_in[6];
  const float* Wv = (const float*)d_in[7];
  const float* Wr = (const float*)d_in[8];
  const float* Wo = (const float*)d_in[9];
  const float* gamma = (const float*)d_in[10];
  const float* beta = (const float*)d_in[11];
  float* out = (float*)d_out;

  // ws layout (ushort units, 1M = 1<<20):
  ushort* hb = (ushort*)d_ws;                       // 8M  concat(mem,x) bf16; later reused as vt
  ushort* Rb = hb + (8u << 20);                     // 1M
  ushort* Wqb = Rb + (1u << 20);                    // 1M
  ushort* Wkb = Wqb + (1u << 20);                   // 1M
  ushort* Wvb = Wkb + (1u << 20);                   // 1M
  ushort* Wrb = Wvb + (1u << 20);                   // 1M
  ushort* Wob = Wrb + (1u << 20);                   // 1M
  ushort* qu_b = Wob + (1u << 20);                  // 4M  (att aliases)
  ushort* qt_b = qu_b + (4u << 20);                 // 4M
  ushort* kb = qt_b + (4u << 20);                   // 8M  (ypre fp32 aliases)
  ushort* vb = kb + (8u << 20);                     // 8M
  ushort* rb = vb + (8u << 20);                     // 1M
  ushort* att = qu_b;
  ushort* vt = hb;   // hb dead after projections
  float* ypre = (float*)kb;

  dim3 blk(256);
  const int NE_X = BB * SS * DD;   // 4M
  const int NE_W = DD * DD;        // 1M

  // casts
  cast_bf16<<<dim3(NE_X / 8 / 256), blk, 0, stream>>>(mem, hb, NE_X, 524288, 0);
  cast_bf16<<<dim3(NE_X / 8 / 256), blk, 0, stream>>>(x, hb, NE_X, 524288, 524288);
  cast_bf16<<<dim3(NE_W / 8 / 256), blk, 0, stream>>>(R, Rb, NE_W, 0, 0);
  cast_bf16<<<dim3(NE_W / 8 / 256), blk, 0, stream>>>(Wq, Wqb, NE_W, 0, 0);
  cast_bf16<<<dim3(NE_W / 8 / 256), blk, 0, stream>>>(Wk, Wkb, NE_W, 0, 0);
  cast_bf16<<<dim3(NE_W / 8 / 256), blk, 0, stream>>>(Wv, Wvb, NE_W, 0, 0);
  cast_bf16<<<dim3(NE_W / 8 / 256), blk, 0, stream>>>(Wr, Wrb, NE_W, 0, 0);
  cast_bf16<<<dim3(NE_W / 8 / 256), blk, 0, stream>>>(Wo, Wob, NE_W, 0, 0);

  // projections (bf16 MFMA)
  gemm_bf16<1, 2><<<dim3(8, 32), blk, 0, stream>>>(hb, Wqb, nullptr, qu_b, qt_b, u, tv);
  gemm_bf16<0, 1><<<dim3(8, 64), blk, 0, stream>>>(hb, Wkb, nullptr, kb, nullptr, nullptr, nullptr);
  gemm_bf16<0, 1><<<dim3(8, 64), blk, 0, stream>>>(hb, Wvb, nullptr, vb, nullptr, nullptr, nullptr);
  gemm_bf16<0, 1><<<dim3(8, 8), blk, 0, stream>>>(Rb, Wrb, nullptr, rb, nullptr, nullptr, nullptr);

  // V transpose into vt (= hb region, dead now)
  transp_v<<<dim3(TT / 64, BB * HH), blk, 0, stream>>>(vb, vt);

  attn_mfma<<<dim3(SS / 64, BB * HH), blk, 0, stream>>>(qu_b, qt_b, kb, vt, rb, att);

  gemm_bf16<0, 0><<<dim3(8, 32), blk, 0, stream>>>(att, Wob, ypre, nullptr, nullptr, nullptr, nullptr);

  ln_kernel<<<dim3(BB * SS), blk, 0, stream>>>(ypre, x, gamma, beta, out);
}

// Round 5
// 266.842 us; speedup vs baseline: 16.9662x; 1.3745x over previous
//
#include <hip/hip_runtime.h>
#include <math.h>

#define BB 8
#define SS 512
#define MM 512
#define TT 1024
#define DD 1024
#define HH 16
#define DH 64

typedef __attribute__((ext_vector_type(8))) short bf16x8;
typedef __attribute__((ext_vector_type(4))) float f32x4;

__device__ __forceinline__ ushort f2bf(float f) {
  union { float f; unsigned u; } x; x.f = f;
  unsigned r = x.u + 0x7fffu + ((x.u >> 16) & 1u);
  return (ushort)(r >> 16);
}

__device__ __forceinline__ void stage16(void* lds, const void* g) {
  __builtin_amdgcn_global_load_lds((const __attribute__((address_space(1))) void*)g,
                                   (__attribute__((address_space(3))) void*)lds, 16, 0, 0);
}

template <int C>
__device__ __forceinline__ float dppf(float x) {
  return __builtin_bit_cast(float,
      __builtin_amdgcn_update_dpp(0, __builtin_bit_cast(int, x), C, 0xF, 0xF, true));
}
// reduce over each 16-lane group: quad xor1, quad xor2, half-mirror, mirror
__device__ __forceinline__ float redmax16(float x) {
  x = fmaxf(x, dppf<0xB1>(x));
  x = fmaxf(x, dppf<0x4E>(x));
  x = fmaxf(x, dppf<0x141>(x));
  x = fmaxf(x, dppf<0x140>(x));
  return x;
}
__device__ __forceinline__ float redsum16(float x) {
  x += dppf<0xB1>(x);
  x += dppf<0x4E>(x);
  x += dppf<0x141>(x);
  x += dppf<0x140>(x);
  return x;
}
__device__ __forceinline__ float bperm_f(int byteaddr, float v) {
  return __builtin_bit_cast(float,
      __builtin_amdgcn_ds_bpermute(byteaddr, __builtin_bit_cast(int, v)));
}

// ---------------------------------------------------------------------------
// fp32 -> bf16 cast, 8 elems/thread. dst_idx = i + (i>>19)*mult + add.
// ---------------------------------------------------------------------------
__global__ __launch_bounds__(256) void cast_bf16(const float* __restrict__ src,
                                                 ushort* __restrict__ dst, int n,
                                                 int mult, int add) {
  int i = (blockIdx.x * 256 + threadIdx.x) * 8;
  if (i >= n) return;
  int b = i >> 19;
  size_t o = (size_t)i + (size_t)b * mult + add;
  float4 a = *(const float4*)(src + i);
  float4 c = *(const float4*)(src + i + 4);
  union { bf16x8 v; ushort u[8]; } pk;
  pk.u[0] = f2bf(a.x); pk.u[1] = f2bf(a.y); pk.u[2] = f2bf(a.z); pk.u[3] = f2bf(a.w);
  pk.u[4] = f2bf(c.x); pk.u[5] = f2bf(c.y); pk.u[6] = f2bf(c.z); pk.u[7] = f2bf(c.w);
  *(bf16x8*)(void*)(dst + o) = pk.v;
}

// ---------------------------------------------------------------------------
// V transpose: vb[b][j][h*64+d] -> vt[(b*16+h)*64+d][j]  (bf16).
// ---------------------------------------------------------------------------
__global__ __launch_bounds__(256) void transp_v(const ushort* __restrict__ vb,
                                                ushort* __restrict__ vt) {
  const int b = blockIdx.y >> 4, h = blockIdx.y & 15;
  const int j0 = blockIdx.x * 64;
  const int t = threadIdx.x;
  __shared__ ushort tile[64][72];  // [d][j]
#pragma unroll
  for (int cc = 0; cc < 2; ++cc) {
    int c = t + cc * 256;
    int jrow = c >> 3, dcol = (c & 7) * 8;
    bf16x8 v = *(const bf16x8*)(const void*)(vb + ((size_t)(b * TT + j0 + jrow)) * DD + h * DH + dcol);
#pragma unroll
    for (int e = 0; e < 8; ++e) tile[dcol + e][jrow] = ((const ushort*)&v)[e];
  }
  __syncthreads();
#pragma unroll
  for (int cc = 0; cc < 2; ++cc) {
    int c = t + cc * 256;
    int d = c >> 3, jcol = (c & 7) * 8;
    bf16x8 o = *(const bf16x8*)(const void*)&tile[d][jcol];
    *(bf16x8*)(void*)(vt + ((size_t)((b * HH + h) * DH + d)) * TT + j0 + jcol) = o;
  }
}

// ---------------------------------------------------------------------------
// MFMA GEMM (m97 structure): C[m][n] = sum_k A[m][k]*W[n][k], bf16 in, fp32 acc.
// ---------------------------------------------------------------------------
template <int ASEL, int MODE>
__global__ __launch_bounds__(256) void gemm_bf16(const ushort* __restrict__ A,
                                                 const ushort* __restrict__ W,
                                                 float* __restrict__ Cf,
                                                 ushort* __restrict__ Cb,
                                                 ushort* __restrict__ C2b,
                                                 const float* __restrict__ uvec,
                                                 const float* __restrict__ tvec) {
  __shared__ ushort As[128 * 32];
  __shared__ ushort Bs[128 * 32];
  const int t = threadIdx.x;
  const int w = t >> 6, l = t & 63;
  const int m16 = l & 15, kg = l >> 4;
  const int m0 = blockIdx.y * 128, n0 = blockIdx.x * 128;
  const int wr = w >> 1, wc = w & 1;

  const int c0 = t, c1 = t + 256;
  const ushort* asrc0;
  const ushort* asrc1;
  {
    int gm0 = m0 + (c0 >> 2), gm1 = m0 + (c1 >> 2);
    if (ASEL == 1) {
      asrc0 = A + ((size_t)((gm0 >> 9) * TT + MM + (gm0 & 511))) * DD + (c0 & 3) * 8;
      asrc1 = A + ((size_t)((gm1 >> 9) * TT + MM + (gm1 & 511))) * DD + (c1 & 3) * 8;
    } else {
      asrc0 = A + (size_t)gm0 * DD + (c0 & 3) * 8;
      asrc1 = A + (size_t)gm1 * DD + (c1 & 3) * 8;
    }
  }
  const ushort* bsrc0 = W + (size_t)(n0 + (c0 >> 2)) * DD + (c0 & 3) * 8;
  const ushort* bsrc1 = W + (size_t)(n0 + (c1 >> 2)) * DD + (c1 & 3) * 8;
  ushort* adst0 = As + c0 * 8;
  ushort* adst1 = As + c1 * 8;
  ushort* bdst0 = Bs + c0 * 8;
  ushort* bdst1 = Bs + c1 * 8;

  f32x4 acc[4][4];
#pragma unroll
  for (int mi = 0; mi < 4; ++mi)
#pragma unroll
    for (int ni = 0; ni < 4; ++ni) acc[mi][ni] = (f32x4){0.f, 0.f, 0.f, 0.f};

  for (int k0 = 0; k0 < DD; k0 += 32) {
    stage16(adst0, asrc0 + k0);
    stage16(adst1, asrc1 + k0);
    stage16(bdst0, bsrc0 + k0);
    stage16(bdst1, bsrc1 + k0);
    __syncthreads();
    bf16x8 af[4], bfr[4];
#pragma unroll
    for (int mi = 0; mi < 4; ++mi)
      af[mi] = *(const bf16x8*)(const void*)&As[(wr * 64 + mi * 16 + m16) * 32 + kg * 8];
#pragma unroll
    for (int ni = 0; ni < 4; ++ni)
      bfr[ni] = *(const bf16x8*)(const void*)&Bs[(wc * 64 + ni * 16 + m16) * 32 + kg * 8];
#pragma unroll
    for (int mi = 0; mi < 4; ++mi)
#pragma unroll
      for (int ni = 0; ni < 4; ++ni)
        acc[mi][ni] = __builtin_amdgcn_mfma_f32_16x16x32_bf16(af[mi], bfr[ni], acc[mi][ni], 0, 0, 0);
    __syncthreads();
  }

  const int rbase = m0 + wr * 64 + kg * 4;
  const int cbase = n0 + wc * 64 + m16;
  if (MODE == 0) {
#pragma unroll
    for (int mi = 0; mi < 4; ++mi)
#pragma unroll
      for (int ni = 0; ni < 4; ++ni)
#pragma unroll
        for (int rg = 0; rg < 4; ++rg)
          Cf[(size_t)(rbase + mi * 16 + rg) * DD + cbase + ni * 16] = acc[mi][ni][rg];
  } else if (MODE == 1) {
#pragma unroll
    for (int mi = 0; mi < 4; ++mi)
#pragma unroll
      for (int ni = 0; ni < 4; ++ni)
#pragma unroll
        for (int rg = 0; rg < 4; ++rg)
          Cb[(size_t)(rbase + mi * 16 + rg) * DD + cbase + ni * 16] = f2bf(acc[mi][ni][rg]);
  } else {
    float uv[4], tv[4];
#pragma unroll
    for (int ni = 0; ni < 4; ++ni) { uv[ni] = uvec[cbase + ni * 16]; tv[ni] = tvec[cbase + ni * 16]; }
#pragma unroll
    for (int mi = 0; mi < 4; ++mi)
#pragma unroll
      for (int ni = 0; ni < 4; ++ni)
#pragma unroll
        for (int rg = 0; rg < 4; ++rg) {
          size_t idx = (size_t)(rbase + mi * 16 + rg) * DD + cbase + ni * 16;
          Cb[idx] = f2bf(acc[mi][ni][rg] + uv[ni]);
          C2b[idx] = f2bf(acc[mi][ni][rg] + tv[ni]);
        }
  }
}

// ---------------------------------------------------------------------------
// MFMA flash attention. 4 waves/block, wave w owns q rows [i0+16w, i0+16w+16).
// K/V tiles staged in LDS via global_load_lds with XOR-swizzled SOURCE addrs
// (linear LDS dest); fragment ds_reads apply the same swizzle -> conflict-free.
// bd circulant gather via ds_bpermute (in-group rotation); pmax/psum via DPP.
// ---------------------------------------------------------------------------
__global__ __launch_bounds__(256) void attn_mfma(const ushort* __restrict__ qu,
                                                 const ushort* __restrict__ qt,
                                                 const ushort* __restrict__ kb,
                                                 const ushort* __restrict__ vt,
                                                 const ushort* __restrict__ rb,
                                                 ushort* __restrict__ att) {
  const int w = threadIdx.x >> 6;
  const int l = threadIdx.x & 63;
  const int m16 = l & 15;
  const int kg = l >> 4;
  const int bh = blockIdx.x;
  const int b = bh >> 4, h = bh & 15;
  const int i0 = blockIdx.y * 64;

  __shared__ ushort Ks[64 * 64];      // [j][k] swizzled
  __shared__ ushort Vs[64 * 64];      // [d][j] swizzled
  __shared__ ushort plds[4][16][72];  // per-wave P tile [q][j]

  // Q fragments
  bf16x8 aqu[2], aqt[2];
  {
    const ushort* qrow = qu + ((size_t)(b * SS + i0 + w * 16 + m16)) * DD + h * DH + kg * 8;
    aqu[0] = *(const bf16x8*)(const void*)(qrow);
    aqu[1] = *(const bf16x8*)(const void*)(qrow + 32);
    const ushort* qrow2 = qt + ((size_t)(b * SS + i0 + w * 16 + m16)) * DD + h * DH + kg * 8;
    aqt[0] = *(const bf16x8*)(const void*)(qrow2);
    aqt[1] = *(const bf16x8*)(const void*)(qrow2 + 32);
  }

  // circulant gather: strip[rw][c] lives at lane kg*16+(c&15), reg f=c>>4, elem rw&3.
  // dest (m16,kg) row rw=kg*4+rg needs c = nt*16 + m16+15-rw -> in-group rotation.
  int baddr[4];
  bool bsel[4];
#pragma unroll
  for (int rg = 0; rg < 4; ++rg) {
    const int rw = kg * 4 + rg;
    baddr[rg] = (kg * 16 + ((m16 + 15 - rw) & 15)) << 2;
    bsel[rg] = m16 > rw;  // wrapped -> take reg f = nt+1
  }

  // staging: chunk c -> LDS bytes [c*16, c*16+16); row=c>>3; source col pre-swizzled
  const int c0 = threadIdx.x, c1 = threadIdx.x + 256;
  const int r0 = c0 >> 3, s0 = ((c0 & 7) * 8) ^ ((r0 & 7) << 3);
  const int r1 = c1 >> 3, s1 = ((c1 & 7) * 8) ^ ((r1 & 7) << 3);
  const ushort* kp0 = kb + ((size_t)(b * TT) + r0) * DD + h * DH + s0;
  const ushort* kp1 = kb + ((size_t)(b * TT) + r1) * DD + h * DH + s1;
  const ushort* vp0 = vt + ((size_t)((b * HH + h) * DH) + r0) * TT + s0;
  const ushort* vp1 = vt + ((size_t)((b * HH + h) * DH) + r1) * TT + s1;
  ushort* kd0 = Ks + c0 * 8;
  ushort* kd1 = Ks + c1 * 8;
  ushort* vd0 = Vs + c0 * 8;
  ushort* vd1 = Vs + c1 * 8;

  const ushort* rlane = rb + h * DH + kg * 8;
  int prowb = 496 - i0 - w * 16 + m16;  // R row for f=0 at j0=0 (always >= 0)

  f32x4 O[4];
  float mrow[4], lrow[4];
#pragma unroll
  for (int nt = 0; nt < 4; ++nt) O[nt] = (f32x4){0.f, 0.f, 0.f, 0.f};
#pragma unroll
  for (int rg = 0; rg < 4; ++rg) { mrow[rg] = -1e30f; lrow[rg] = 0.f; }

  const int ntj = i0 / 64 + 9;
  for (int jt = 0; jt < ntj; ++jt) {
    const int j0 = jt * 64;

    // ---- stage K/V tile (block-shared), issue R loads; barrier drains all ----
    stage16(kd0, kp0); stage16(kd1, kp1);
    stage16(vd0, vp0); stage16(vd1, vp1);
    kp0 += (size_t)64 * DD; kp1 += (size_t)64 * DD;
    vp0 += 64; vp1 += 64;

    bf16x8 br[5][2];
#pragma unroll
    for (int f = 0; f < 5; ++f) {
      int pr = prowb + f * 16;
      pr = pr < 1023 ? pr : 1023;  // clamped rows feed masked entries only
      const ushort* rr = rlane + ((size_t)pr << 10);
      br[f][0] = *(const bf16x8*)(const void*)rr;
      br[f][1] = *(const bf16x8*)(const void*)(rr + 32);
    }
    prowb += 64;

    __syncthreads();

    // ---- ac = qu . K^T (K frags from swizzled LDS) ----
    f32x4 ac[4];
#pragma unroll
    for (int nt = 0; nt < 4; ++nt) {
      ac[nt] = (f32x4){0.f, 0.f, 0.f, 0.f};
      const int row = nt * 16 + m16;
#pragma unroll
      for (int ks = 0; ks < 2; ++ks) {
        const char* p = (const char*)Ks + row * 128 + ((kg * 16 + ks * 64) ^ ((row & 7) << 4));
        bf16x8 bk = *(const bf16x8*)(const void*)p;
        ac[nt] = __builtin_amdgcn_mfma_f32_16x16x32_bf16(aqu[ks], bk, ac[nt], 0, 0, 0);
      }
    }

    // ---- bd strip 16x80 ----
    f32x4 bd[5];
#pragma unroll
    for (int f = 0; f < 5; ++f) {
      f32x4 z = (f32x4){0.f, 0.f, 0.f, 0.f};
      z = __builtin_amdgcn_mfma_f32_16x16x32_bf16(aqt[0], br[f][0], z, 0, 0, 0);
      bd[f] = __builtin_amdgcn_mfma_f32_16x16x32_bf16(aqt[1], br[f][1], z, 0, 0, 0);
    }

    // ---- gather (bpermute) + scale + mask + rowmax (DPP) ----
    float sca[4][4];
    float pmax[4];
#pragma unroll
    for (int rg = 0; rg < 4; ++rg) {
      float rr[5];
#pragma unroll
      for (int f = 0; f < 5; ++f) rr[f] = bperm_f(baddr[rg], bd[f][rg]);
      const int jmax = i0 + w * 16 + kg * 4 + rg + MM;
      float pm = -1e30f;
#pragma unroll
      for (int nt = 0; nt < 4; ++nt) {
        float bdv = bsel[rg] ? rr[nt + 1] : rr[nt];
        float s = (ac[nt][rg] + bdv) * 0.125f;
        s = (j0 + nt * 16 + m16 <= jmax) ? s : -1e30f;
        sca[nt][rg] = s;
        pm = fmaxf(pm, s);
      }
      pmax[rg] = redmax16(pm);
    }

    // ---- defer-max rescale (THR=8) ----
    bool grow = false;
#pragma unroll
    for (int rg = 0; rg < 4; ++rg) grow = grow || (pmax[rg] > mrow[rg] + 8.f);
    if (__any(grow)) {
#pragma unroll
      for (int rg = 0; rg < 4; ++rg) {
        float mnew = fmaxf(mrow[rg], pmax[rg]);
        float scale = __expf(mrow[rg] - mnew);
        mrow[rg] = mnew;
        lrow[rg] *= scale;
#pragma unroll
        for (int nt = 0; nt < 4; ++nt) O[nt][rg] *= scale;
      }
    }

    // ---- p = exp(s-m), row-sum (DPP), P -> plds ----
#pragma unroll
    for (int rg = 0; rg < 4; ++rg) {
      float ps = 0.f;
#pragma unroll
      for (int nt = 0; nt < 4; ++nt) {
        float p = __expf(sca[nt][rg] - mrow[rg]);
        ps += p;
        plds[w][kg * 4 + rg][nt * 16 + m16] = f2bf(p);
      }
      lrow[rg] += redsum16(ps);
    }

    // ---- PV: O += P . V (V frags from swizzled LDS) ----
#pragma unroll
    for (int ks = 0; ks < 2; ++ks) {
      bf16x8 pa = *(const bf16x8*)(const void*)&plds[w][m16][kg * 8 + ks * 32];
#pragma unroll
      for (int nt = 0; nt < 4; ++nt) {
        const int row = nt * 16 + m16;
        const char* p = (const char*)Vs + row * 128 + ((kg * 16 + ks * 64) ^ ((row & 7) << 4));
        bf16x8 vf = *(const bf16x8*)(const void*)p;
        O[nt] = __builtin_amdgcn_mfma_f32_16x16x32_bf16(pa, vf, O[nt], 0, 0, 0);
      }
    }

    __syncthreads();
  }

  // ---- epilogue ----
  float linv[4];
#pragma unroll
  for (int rg = 0; rg < 4; ++rg) linv[rg] = 1.f / lrow[rg];
#pragma unroll
  for (int nt = 0; nt < 4; ++nt) {
#pragma unroll
    for (int rg = 0; rg < 4; ++rg) {
      att[((size_t)(b * SS + i0 + w * 16 + kg * 4 + rg)) * DD + h * DH + nt * 16 + m16] =
          f2bf(O[nt][rg] * linv[rg]);
    }
  }
}

// ---------------------------------------------------------------------------
// LayerNorm over y = ypre + x.
// ---------------------------------------------------------------------------
__global__ __launch_bounds__(256) void ln_kernel(const float* __restrict__ ypre,
                                                 const float* __restrict__ x,
                                                 const float* __restrict__ gamma,
                                                 const float* __restrict__ beta,
                                                 float* __restrict__ out) {
  const int row = blockIdx.x;
  const int t = threadIdx.x;
  const int lane = t & 63, w = t >> 6;
  const float* yr = ypre + (size_t)row * DD;
  const float* xr = x + (size_t)row * DD;

  float4 yv = *(const float4*)(yr + t * 4);
  float4 xv = *(const float4*)(xr + t * 4);
  float v0 = yv.x + xv.x, v1 = yv.y + xv.y, v2 = yv.z + xv.z, v3 = yv.w + xv.w;

  float s = v0 + v1 + v2 + v3;
  float ss = v0 * v0 + v1 * v1 + v2 * v2 + v3 * v3;
  __shared__ float rs[4], rss[4];
#pragma unroll
  for (int off = 32; off; off >>= 1) {
    s += __shfl_xor(s, off);
    ss += __shfl_xor(ss, off);
  }
  if (!lane) { rs[w] = s; rss[w] = ss; }
  __syncthreads();
  s = rs[0] + rs[1] + rs[2] + rs[3];
  ss = rss[0] + rss[1] + rss[2] + rss[3];
  const float mu = s * (1.f / DD);
  const float var = ss * (1.f / DD) - mu * mu;
  const float rstd = rsqrtf(var + 1e-5f);

  float4 g = *(const float4*)(gamma + t * 4);
  float4 be = *(const float4*)(beta + t * 4);
  float4 o;
  o.x = (v0 - mu) * rstd * g.x + be.x;
  o.y = (v1 - mu) * rstd * g.y + be.y;
  o.z = (v2 - mu) * rstd * g.z + be.z;
  o.w = (v3 - mu) * rstd * g.w + be.w;
  *(float4*)(out + (size_t)row * DD + t * 4) = o;
}

// ---------------------------------------------------------------------------
extern "C" void kernel_launch(void* const* d_in, const int* in_sizes, int n_in,
                              void* d_out, int out_size, void* d_ws, size_t ws_size,
                              hipStream_t stream) {
  const float* x = (const float*)d_in[0];
  const float* mem = (const float*)d_in[1];
  const float* R = (const float*)d_in[2];
  const float* u = (const float*)d_in[3];
  const float* tv = (const float*)d_in[4];
  const float* Wq = (const float*)d_in[5];
  const float* Wk = (const float*)d_in[6];
  const float* Wv = (const float*)d_in[7];
  const float* Wr = (const float*)d_in[8];
  const float* Wo = (const float*)d_in[9];
  const float* gamma = (const float*)d_in[10];
  const float* beta = (const float*)d_in[11];
  float* out = (float*)d_out;

  // ws layout (ushort units, 1M = 1<<20):
  ushort* hb = (ushort*)d_ws;                       // 8M  concat(mem,x) bf16; reused as vt
  ushort* Rb = hb + (8u << 20);                     // 1M
  ushort* Wqb = Rb + (1u << 20);                    // 1M
  ushort* Wkb = Wqb + (1u << 20);                   // 1M
  ushort* Wvb = Wkb + (1u << 20);                   // 1M
  ushort* Wrb = Wvb + (1u << 20);                   // 1M
  ushort* Wob = Wrb + (1u << 20);                   // 1M
  ushort* qu_b = Wob + (1u << 20);                  // 4M  (att aliases)
  ushort* qt_b = qu_b + (4u << 20);                 // 4M
  ushort* kb = qt_b + (4u << 20);                   // 8M  (ypre fp32 aliases)
  ushort* vb = kb + (8u << 20);                     // 8M
  ushort* rb = vb + (8u << 20);                     // 1M
  ushort* att = qu_b;
  ushort* vt = hb;   // hb dead after projections
  float* ypre = (float*)kb;

  dim3 blk(256);
  const int NE_X = BB * SS * DD;   // 4M
  const int NE_W = DD * DD;        // 1M

  // casts
  cast_bf16<<<dim3(NE_X / 8 / 256), blk, 0, stream>>>(mem, hb, NE_X, 524288, 0);
  cast_bf16<<<dim3(NE_X / 8 / 256), blk, 0, stream>>>(x, hb, NE_X, 524288, 524288);
  cast_bf16<<<dim3(NE_W / 8 / 256), blk, 0, stream>>>(R, Rb, NE_W, 0, 0);
  cast_bf16<<<dim3(NE_W / 8 / 256), blk, 0, stream>>>(Wq, Wqb, NE_W, 0, 0);
  cast_bf16<<<dim3(NE_W / 8 / 256), blk, 0, stream>>>(Wk, Wkb, NE_W, 0, 0);
  cast_bf16<<<dim3(NE_W / 8 / 256), blk, 0, stream>>>(Wv, Wvb, NE_W, 0, 0);
  cast_bf16<<<dim3(NE_W / 8 / 256), blk, 0, stream>>>(Wr, Wrb, NE_W, 0, 0);
  cast_bf16<<<dim3(NE_W / 8 / 256), blk, 0, stream>>>(Wo, Wob, NE_W, 0, 0);

  // projections (bf16 MFMA)
  gemm_bf16<1, 2><<<dim3(8, 32), blk, 0, stream>>>(hb, Wqb, nullptr, qu_b, qt_b, u, tv);
  gemm_bf16<0, 1><<<dim3(8, 64), blk, 0, stream>>>(hb, Wkb, nullptr, kb, nullptr, nullptr, nullptr);
  gemm_bf16<0, 1><<<dim3(8, 64), blk, 0, stream>>>(hb, Wvb, nullptr, vb, nullptr, nullptr, nullptr);
  gemm_bf16<0, 1><<<dim3(8, 8), blk, 0, stream>>>(Rb, Wrb, nullptr, rb, nullptr, nullptr, nullptr);

  // V transpose into vt (= hb region, dead now)
  transp_v<<<dim3(TT / 64, BB * HH), blk, 0, stream>>>(vb, vt);

  // attention: grid (bh, i-tile) so XCD round-robin balances the ntj spread
  attn_mfma<<<dim3(BB * HH, SS / 64), blk, 0, stream>>>(qu_b, qt_b, kb, vt, rb, att);

  gemm_bf16<0, 0><<<dim3(8, 32), blk, 0, stream>>>(att, Wob, ypre, nullptr, nullptr, nullptr, nullptr);

  ln_kernel<<<dim3(BB * SS), blk, 0, stream>>>(ypre, x, gamma, beta, out);
}

// Round 6
// 263.700 us; speedup vs baseline: 17.1683x; 1.0119x over previous
//
#include <hip/hip_runtime.h>
#include <math.h>

#define BB 8
#define SS 512
#define MM 512
#define TT 1024
#define DD 1024
#define HH 16
#define DH 64

typedef __attribute__((ext_vector_type(8))) short bf16x8;
typedef __attribute__((ext_vector_type(4))) float f32x4;

#define SCL2E 0.1803368801111f  /* 0.125 * log2(e) */
#define DTHR 11.5f              /* defer-max threshold in log2 units */

__device__ __forceinline__ ushort f2bf(float f) {
  union { float f; unsigned u; } x; x.f = f;
  unsigned r = x.u + 0x7fffu + ((x.u >> 16) & 1u);
  return (ushort)(r >> 16);
}

__device__ __forceinline__ void stage16(void* lds, const void* g) {
  __builtin_amdgcn_global_load_lds((const __attribute__((address_space(1))) void*)g,
                                   (__attribute__((address_space(3))) void*)lds, 16, 0, 0);
}

template <int C>
__device__ __forceinline__ float dppf(float x) {
  return __builtin_bit_cast(float,
      __builtin_amdgcn_update_dpp(0, __builtin_bit_cast(int, x), C, 0xF, 0xF, true));
}
__device__ __forceinline__ float redmax16(float x) {
  x = fmaxf(x, dppf<0xB1>(x));
  x = fmaxf(x, dppf<0x4E>(x));
  x = fmaxf(x, dppf<0x141>(x));
  x = fmaxf(x, dppf<0x140>(x));
  return x;
}
__device__ __forceinline__ float redsum16(float x) {
  x += dppf<0xB1>(x);
  x += dppf<0x4E>(x);
  x += dppf<0x141>(x);
  x += dppf<0x140>(x);
  return x;
}
__device__ __forceinline__ float bperm_f(int byteaddr, float v) {
  return __builtin_bit_cast(float,
      __builtin_amdgcn_ds_bpermute(byteaddr, __builtin_bit_cast(int, v)));
}

// ---------------------------------------------------------------------------
// One fused cast kernel: fp32->bf16 for all inputs. Segments (compile-time):
// [0,4M) mem->hb interleaved; [4M,8M) x->hb interleaved; [8M,9M) R;
// then Wq,Wk,Wv,Wr,Wo (1M each). 8 elems/thread.
// ---------------------------------------------------------------------------
__global__ __launch_bounds__(256) void cast_all(
    const float* __restrict__ mem, const float* __restrict__ x,
    const float* __restrict__ R, const float* __restrict__ Wq,
    const float* __restrict__ Wk, const float* __restrict__ Wv,
    const float* __restrict__ Wr, const float* __restrict__ Wo,
    ushort* __restrict__ hb, ushort* __restrict__ Rb, ushort* __restrict__ Wqb,
    ushort* __restrict__ Wkb, ushort* __restrict__ Wvb, ushort* __restrict__ Wrb,
    ushort* __restrict__ Wob) {
  const int M1 = 1 << 20;
  int i = (blockIdx.x * 256 + threadIdx.x) * 8;
  const float* src;
  ushort* dst;
  if (i < 4 * M1) {
    src = mem + i;
    dst = hb + (size_t)i + (size_t)(i >> 19) * 524288;
  } else if (i < 8 * M1) {
    int j = i - 4 * M1;
    src = x + j;
    dst = hb + (size_t)j + (size_t)(j >> 19) * 524288 + 524288;
  } else if (i < 9 * M1) {
    src = R + (i - 8 * M1);  dst = Rb + (i - 8 * M1);
  } else if (i < 10 * M1) {
    src = Wq + (i - 9 * M1); dst = Wqb + (i - 9 * M1);
  } else if (i < 11 * M1) {
    src = Wk + (i - 10 * M1); dst = Wkb + (i - 10 * M1);
  } else if (i < 12 * M1) {
    src = Wv + (i - 11 * M1); dst = Wvb + (i - 11 * M1);
  } else if (i < 13 * M1) {
    src = Wr + (i - 12 * M1); dst = Wrb + (i - 12 * M1);
  } else {
    src = Wo + (i - 13 * M1); dst = Wob + (i - 13 * M1);
  }
  float4 a = *(const float4*)(src);
  float4 c = *(const float4*)(src + 4);
  union { bf16x8 v; ushort u[8]; } pk;
  pk.u[0] = f2bf(a.x); pk.u[1] = f2bf(a.y); pk.u[2] = f2bf(a.z); pk.u[3] = f2bf(a.w);
  pk.u[4] = f2bf(c.x); pk.u[5] = f2bf(c.y); pk.u[6] = f2bf(c.z); pk.u[7] = f2bf(c.w);
  *(bf16x8*)(void*)dst = pk.v;
}

// ---------------------------------------------------------------------------
// V transpose: vb[b][j][h*64+d] -> vt[(b*16+h)*64+d][j]  (bf16).
// ---------------------------------------------------------------------------
__global__ __launch_bounds__(256) void transp_v(const ushort* __restrict__ vb,
                                                ushort* __restrict__ vt) {
  const int b = blockIdx.y >> 4, h = blockIdx.y & 15;
  const int j0 = blockIdx.x * 64;
  const int t = threadIdx.x;
  __shared__ ushort tile[64][72];  // [d][j]
#pragma unroll
  for (int cc = 0; cc < 2; ++cc) {
    int c = t + cc * 256;
    int jrow = c >> 3, dcol = (c & 7) * 8;
    bf16x8 v = *(const bf16x8*)(const void*)(vb + ((size_t)(b * TT + j0 + jrow)) * DD + h * DH + dcol);
#pragma unroll
    for (int e = 0; e < 8; ++e) tile[dcol + e][jrow] = ((const ushort*)&v)[e];
  }
  __syncthreads();
#pragma unroll
  for (int cc = 0; cc < 2; ++cc) {
    int c = t + cc * 256;
    int d = c >> 3, jcol = (c & 7) * 8;
    bf16x8 o = *(const bf16x8*)(const void*)&tile[d][jcol];
    *(bf16x8*)(void*)(vt + ((size_t)((b * HH + h) * DH + d)) * TT + j0 + jcol) = o;
  }
}

// ---------------------------------------------------------------------------
// Fused q/k/v/r projection GEMM (m97 structure), one launch, 1344 blocks.
// bid<256: q (dual out +u/+t, A = x-slice of hb); <768: k; <1280: v; else r.
// ---------------------------------------------------------------------------
__global__ __launch_bounds__(256) void gemm_qkvr(
    const ushort* __restrict__ hb, const ushort* __restrict__ Rbuf,
    const ushort* __restrict__ Wqb, const ushort* __restrict__ Wkb,
    const ushort* __restrict__ Wvb, const ushort* __restrict__ Wrb,
    ushort* __restrict__ qub, ushort* __restrict__ qtb,
    ushort* __restrict__ kbo, ushort* __restrict__ vbo, ushort* __restrict__ rbo,
    const float* __restrict__ uvec, const float* __restrict__ tvec) {
  __shared__ ushort As[128 * 32];
  __shared__ ushort Bs[128 * 32];
  const int bid = blockIdx.x;
  const ushort* A;
  const ushort* W;
  ushort* C0;
  ushort* C1 = nullptr;
  bool dual = false, qslice = false;
  int mt, nx;
  if (bid < 256) {
    int r = bid; mt = r >> 3; nx = r & 7;
    A = hb; W = Wqb; C0 = qub; C1 = qtb; dual = true; qslice = true;
  } else if (bid < 768) {
    int r = bid - 256; mt = r >> 3; nx = r & 7;
    A = hb; W = Wkb; C0 = kbo;
  } else if (bid < 1280) {
    int r = bid - 768; mt = r >> 3; nx = r & 7;
    A = hb; W = Wvb; C0 = vbo;
  } else {
    int r = bid - 1280; mt = r >> 3; nx = r & 7;
    A = Rbuf; W = Wrb; C0 = rbo;
  }
  const int m0 = mt * 128, n0 = nx * 128;

  const int t = threadIdx.x;
  const int w = t >> 6, l = t & 63;
  const int m16 = l & 15, kg = l >> 4;
  const int wr = w >> 1, wc = w & 1;

  const int c0 = t, c1 = t + 256;
  const ushort* asrc0;
  const ushort* asrc1;
  {
    int gm0 = m0 + (c0 >> 2), gm1 = m0 + (c1 >> 2);
    if (qslice) {
      asrc0 = A + ((size_t)((gm0 >> 9) * TT + MM + (gm0 & 511))) * DD + (c0 & 3) * 8;
      asrc1 = A + ((size_t)((gm1 >> 9) * TT + MM + (gm1 & 511))) * DD + (c1 & 3) * 8;
    } else {
      asrc0 = A + (size_t)gm0 * DD + (c0 & 3) * 8;
      asrc1 = A + (size_t)gm1 * DD + (c1 & 3) * 8;
    }
  }
  const ushort* bsrc0 = W + (size_t)(n0 + (c0 >> 2)) * DD + (c0 & 3) * 8;
  const ushort* bsrc1 = W + (size_t)(n0 + (c1 >> 2)) * DD + (c1 & 3) * 8;
  ushort* adst0 = As + c0 * 8;
  ushort* adst1 = As + c1 * 8;
  ushort* bdst0 = Bs + c0 * 8;
  ushort* bdst1 = Bs + c1 * 8;

  f32x4 acc[4][4];
#pragma unroll
  for (int mi = 0; mi < 4; ++mi)
#pragma unroll
    for (int ni = 0; ni < 4; ++ni) acc[mi][ni] = (f32x4){0.f, 0.f, 0.f, 0.f};

  for (int k0 = 0; k0 < DD; k0 += 32) {
    stage16(adst0, asrc0 + k0);
    stage16(adst1, asrc1 + k0);
    stage16(bdst0, bsrc0 + k0);
    stage16(bdst1, bsrc1 + k0);
    __syncthreads();
    bf16x8 af[4], bfr[4];
#pragma unroll
    for (int mi = 0; mi < 4; ++mi)
      af[mi] = *(const bf16x8*)(const void*)&As[(wr * 64 + mi * 16 + m16) * 32 + kg * 8];
#pragma unroll
    for (int ni = 0; ni < 4; ++ni)
      bfr[ni] = *(const bf16x8*)(const void*)&Bs[(wc * 64 + ni * 16 + m16) * 32 + kg * 8];
#pragma unroll
    for (int mi = 0; mi < 4; ++mi)
#pragma unroll
      for (int ni = 0; ni < 4; ++ni)
        acc[mi][ni] = __builtin_amdgcn_mfma_f32_16x16x32_bf16(af[mi], bfr[ni], acc[mi][ni], 0, 0, 0);
    __syncthreads();
  }

  const int rbase = m0 + wr * 64 + kg * 4;
  const int cbase = n0 + wc * 64 + m16;
  if (dual) {
    float uv[4], tv[4];
#pragma unroll
    for (int ni = 0; ni < 4; ++ni) { uv[ni] = uvec[cbase + ni * 16]; tv[ni] = tvec[cbase + ni * 16]; }
#pragma unroll
    for (int mi = 0; mi < 4; ++mi)
#pragma unroll
      for (int ni = 0; ni < 4; ++ni)
#pragma unroll
        for (int rg = 0; rg < 4; ++rg) {
          size_t idx = (size_t)(rbase + mi * 16 + rg) * DD + cbase + ni * 16;
          C0[idx] = f2bf(acc[mi][ni][rg] + uv[ni]);
          C1[idx] = f2bf(acc[mi][ni][rg] + tv[ni]);
        }
  } else {
#pragma unroll
    for (int mi = 0; mi < 4; ++mi)
#pragma unroll
      for (int ni = 0; ni < 4; ++ni)
#pragma unroll
        for (int rg = 0; rg < 4; ++rg)
          C0[(size_t)(rbase + mi * 16 + rg) * DD + cbase + ni * 16] = f2bf(acc[mi][ni][rg]);
  }
}

// ---------------------------------------------------------------------------
// MFMA GEMM for Wo: fp32 out (m97 structure).
// ---------------------------------------------------------------------------
__global__ __launch_bounds__(256) void gemm_wo(const ushort* __restrict__ A,
                                               const ushort* __restrict__ W,
                                               float* __restrict__ Cf) {
  __shared__ ushort As[128 * 32];
  __shared__ ushort Bs[128 * 32];
  const int t = threadIdx.x;
  const int w = t >> 6, l = t & 63;
  const int m16 = l & 15, kg = l >> 4;
  const int m0 = blockIdx.y * 128, n0 = blockIdx.x * 128;
  const int wr = w >> 1, wc = w & 1;

  const int c0 = t, c1 = t + 256;
  const ushort* asrc0 = A + (size_t)(m0 + (c0 >> 2)) * DD + (c0 & 3) * 8;
  const ushort* asrc1 = A + (size_t)(m0 + (c1 >> 2)) * DD + (c1 & 3) * 8;
  const ushort* bsrc0 = W + (size_t)(n0 + (c0 >> 2)) * DD + (c0 & 3) * 8;
  const ushort* bsrc1 = W + (size_t)(n0 + (c1 >> 2)) * DD + (c1 & 3) * 8;
  ushort* adst0 = As + c0 * 8;
  ushort* adst1 = As + c1 * 8;
  ushort* bdst0 = Bs + c0 * 8;
  ushort* bdst1 = Bs + c1 * 8;

  f32x4 acc[4][4];
#pragma unroll
  for (int mi = 0; mi < 4; ++mi)
#pragma unroll
    for (int ni = 0; ni < 4; ++ni) acc[mi][ni] = (f32x4){0.f, 0.f, 0.f, 0.f};

  for (int k0 = 0; k0 < DD; k0 += 32) {
    stage16(adst0, asrc0 + k0);
    stage16(adst1, asrc1 + k0);
    stage16(bdst0, bsrc0 + k0);
    stage16(bdst1, bsrc1 + k0);
    __syncthreads();
    bf16x8 af[4], bfr[4];
#pragma unroll
    for (int mi = 0; mi < 4; ++mi)
      af[mi] = *(const bf16x8*)(const void*)&As[(wr * 64 + mi * 16 + m16) * 32 + kg * 8];
#pragma unroll
    for (int ni = 0; ni < 4; ++ni)
      bfr[ni] = *(const bf16x8*)(const void*)&Bs[(wc * 64 + ni * 16 + m16) * 32 + kg * 8];
#pragma unroll
    for (int mi = 0; mi < 4; ++mi)
#pragma unroll
      for (int ni = 0; ni < 4; ++ni)
        acc[mi][ni] = __builtin_amdgcn_mfma_f32_16x16x32_bf16(af[mi], bfr[ni], acc[mi][ni], 0, 0, 0);
    __syncthreads();
  }

  const int rbase = m0 + wr * 64 + kg * 4;
  const int cbase = n0 + wc * 64 + m16;
#pragma unroll
  for (int mi = 0; mi < 4; ++mi)
#pragma unroll
    for (int ni = 0; ni < 4; ++ni)
#pragma unroll
      for (int rg = 0; rg < 4; ++rg)
        Cf[(size_t)(rbase + mi * 16 + rg) * DD + cbase + ni * 16] = acc[mi][ni][rg];
}

// ---------------------------------------------------------------------------
// MFMA flash attention. 4 waves/block. K double-buffered in LDS with
// prefetch + ONE barrier per j-tile (T3-lite 2-phase). V direct-from-global
// (pre-transposed vt). bd gather via ds_bpermute; reductions via DPP.
// Softmax in log2 domain; mask applied only on the last j-tile.
// ---------------------------------------------------------------------------
__global__ __launch_bounds__(256, 4) void attn_mfma(const ushort* __restrict__ qu,
                                                    const ushort* __restrict__ qt,
                                                    const ushort* __restrict__ kb,
                                                    const ushort* __restrict__ vt,
                                                    const ushort* __restrict__ rb,
                                                    ushort* __restrict__ att) {
  const int w = threadIdx.x >> 6;
  const int l = threadIdx.x & 63;
  const int m16 = l & 15;
  const int kg = l >> 4;
  const int bh = blockIdx.x;
  const int b = bh >> 4, h = bh & 15;
  const int i0 = blockIdx.y * 64;

  __shared__ ushort Ks[2][64 * 64];   // [j][k] swizzled, double-buffered
  __shared__ ushort plds[4][16][72];  // per-wave P tile [q][j]

  // Q fragments
  bf16x8 aqu[2], aqt[2];
  {
    const ushort* qrow = qu + ((size_t)(b * SS + i0 + w * 16 + m16)) * DD + h * DH + kg * 8;
    aqu[0] = *(const bf16x8*)(const void*)(qrow);
    aqu[1] = *(const bf16x8*)(const void*)(qrow + 32);
    const ushort* qrow2 = qt + ((size_t)(b * SS + i0 + w * 16 + m16)) * DD + h * DH + kg * 8;
    aqt[0] = *(const bf16x8*)(const void*)(qrow2);
    aqt[1] = *(const bf16x8*)(const void*)(qrow2 + 32);
  }

  // circulant gather lane addressing (round-5 verified)
  int baddr[4];
  bool bsel[4];
#pragma unroll
  for (int rg = 0; rg < 4; ++rg) {
    const int rw = kg * 4 + rg;
    baddr[rg] = (kg * 16 + ((m16 + 15 - rw) & 15)) << 2;
    bsel[rg] = m16 > rw;
  }

  // K staging: chunk c -> LDS [c*16, c*16+16); row=c>>3; source col pre-swizzled
  const int c0 = threadIdx.x, c1 = threadIdx.x + 256;
  const int r0 = c0 >> 3, s0 = ((c0 & 7) * 8) ^ ((r0 & 7) << 3);
  const int r1 = c1 >> 3, s1 = ((c1 & 7) * 8) ^ ((r1 & 7) << 3);
  const ushort* kp0 = kb + ((size_t)(b * TT) + r0) * DD + h * DH + s0;
  const ushort* kp1 = kb + ((size_t)(b * TT) + r1) * DD + h * DH + s1;

  const ushort* vlane = vt + ((size_t)((b * HH + h) * DH) + m16) * TT + kg * 8;
  const ushort* rlane = rb + h * DH + kg * 8;
  int prowb = 496 - i0 - w * 16 + m16;

  f32x4 O[4];
  float mrow[4], lrow[4];
#pragma unroll
  for (int nt = 0; nt < 4; ++nt) O[nt] = (f32x4){0.f, 0.f, 0.f, 0.f};
#pragma unroll
  for (int rg = 0; rg < 4; ++rg) { mrow[rg] = -1e30f; lrow[rg] = 0.f; }

  const int ntj = i0 / 64 + 9;

  // prologue: stage tile 0 into buffer 0
  stage16(&Ks[0][c0 * 8], kp0);
  stage16(&Ks[0][c1 * 8], kp1);
  kp0 += (size_t)64 * DD;
  kp1 += (size_t)64 * DD;
  __syncthreads();

  int cur = 0;
  for (int jt = 0; jt < ntj; ++jt) {
    const int j0 = jt * 64;

    // ---- prefetch K(t+1) into other buffer (drained at this iter's barrier) ----
    if (jt + 1 < ntj) {
      stage16(&Ks[cur ^ 1][c0 * 8], kp0);
      stage16(&Ks[cur ^ 1][c1 * 8], kp1);
      kp0 += (size_t)64 * DD;
      kp1 += (size_t)64 * DD;
    }

    // ---- R loads (consumed by bd) ----
    bf16x8 br[5][2];
#pragma unroll
    for (int f = 0; f < 5; ++f) {
      int pr = prowb + f * 16;
      pr = pr < 1023 ? pr : 1023;  // clamped rows feed masked entries only
      const ushort* rr = rlane + ((size_t)pr << 10);
      br[f][0] = *(const bf16x8*)(const void*)rr;
      br[f][1] = *(const bf16x8*)(const void*)(rr + 32);
    }
    prowb += 64;

    // ---- ac = qu . K^T (swizzled LDS reads) ----
    f32x4 ac[4];
#pragma unroll
    for (int nt = 0; nt < 4; ++nt) {
      ac[nt] = (f32x4){0.f, 0.f, 0.f, 0.f};
      const int row = nt * 16 + m16;
#pragma unroll
      for (int ks = 0; ks < 2; ++ks) {
        const char* p = (const char*)&Ks[cur][0] + row * 128 + ((kg * 16 + ks * 64) ^ ((row & 7) << 4));
        bf16x8 bk = *(const bf16x8*)(const void*)p;
        ac[nt] = __builtin_amdgcn_mfma_f32_16x16x32_bf16(aqu[ks], bk, ac[nt], 0, 0, 0);
      }
    }

    // ---- bd strip 16x80 ----
    f32x4 bd[5];
#pragma unroll
    for (int f = 0; f < 5; ++f) {
      f32x4 z = (f32x4){0.f, 0.f, 0.f, 0.f};
      z = __builtin_amdgcn_mfma_f32_16x16x32_bf16(aqt[0], br[f][0], z, 0, 0, 0);
      bd[f] = __builtin_amdgcn_mfma_f32_16x16x32_bf16(aqt[1], br[f][1], z, 0, 0, 0);
    }

    // ---- V loads for this tile (consumed by PV; latency hidden under softmax) ----
    bf16x8 vf[2][4];
#pragma unroll
    for (int ks = 0; ks < 2; ++ks)
#pragma unroll
      for (int nt = 0; nt < 4; ++nt)
        vf[ks][nt] = *(const bf16x8*)(const void*)(vlane + (size_t)(nt * 16) * TT + j0 + ks * 32);

    // ---- gather + scale (log2 domain) ----
    float sca[4][4];
#pragma unroll
    for (int rg = 0; rg < 4; ++rg) {
      float rr[5];
#pragma unroll
      for (int f = 0; f < 5; ++f) rr[f] = bperm_f(baddr[rg], bd[f][rg]);
#pragma unroll
      for (int nt = 0; nt < 4; ++nt) {
        float bdv = bsel[rg] ? rr[nt + 1] : rr[nt];
        sca[nt][rg] = (ac[nt][rg] + bdv) * SCL2E;
      }
    }
    // mask only the last j-tile (all earlier tiles fully valid)
    if (jt == ntj - 1) {
#pragma unroll
      for (int rg = 0; rg < 4; ++rg) {
        const int jmax = i0 + w * 16 + kg * 4 + rg + MM;
#pragma unroll
        for (int nt = 0; nt < 4; ++nt)
          sca[nt][rg] = (j0 + nt * 16 + m16 <= jmax) ? sca[nt][rg] : -1e30f;
      }
    }

    // ---- rowmax (DPP) + defer-max rescale ----
    float pmax[4];
#pragma unroll
    for (int rg = 0; rg < 4; ++rg) {
      float pm = fmaxf(fmaxf(sca[0][rg], sca[1][rg]), fmaxf(sca[2][rg], sca[3][rg]));
      pmax[rg] = redmax16(pm);
    }
    bool grow = false;
#pragma unroll
    for (int rg = 0; rg < 4; ++rg) grow = grow || (pmax[rg] > mrow[rg] + DTHR);
    if (__any(grow)) {
#pragma unroll
      for (int rg = 0; rg < 4; ++rg) {
        float mnew = fmaxf(mrow[rg], pmax[rg]);
        float scale = __builtin_amdgcn_exp2f(mrow[rg] - mnew);
        mrow[rg] = mnew;
        lrow[rg] *= scale;
#pragma unroll
        for (int nt = 0; nt < 4; ++nt) O[nt][rg] *= scale;
      }
    }

    // ---- p = exp2(s-m), row-sum (DPP), P -> plds ----
#pragma unroll
    for (int rg = 0; rg < 4; ++rg) {
      float ps = 0.f;
#pragma unroll
      for (int nt = 0; nt < 4; ++nt) {
        float p = __builtin_amdgcn_exp2f(sca[nt][rg] - mrow[rg]);
        ps += p;
        plds[w][kg * 4 + rg][nt * 16 + m16] = f2bf(p);
      }
      lrow[rg] += redsum16(ps);
    }

    // ---- PV ----
#pragma unroll
    for (int ks = 0; ks < 2; ++ks) {
      bf16x8 pa = *(const bf16x8*)(const void*)&plds[w][m16][kg * 8 + ks * 32];
#pragma unroll
      for (int nt = 0; nt < 4; ++nt)
        O[nt] = __builtin_amdgcn_mfma_f32_16x16x32_bf16(pa, vf[ks][nt], O[nt], 0, 0, 0);
    }

    __syncthreads();  // K(t+1) staged (issued ~full iter ago); buf[cur] reads done
    cur ^= 1;
  }

  // ---- epilogue ----
  float linv[4];
#pragma unroll
  for (int rg = 0; rg < 4; ++rg) linv[rg] = 1.f / lrow[rg];
#pragma unroll
  for (int nt = 0; nt < 4; ++nt) {
#pragma unroll
    for (int rg = 0; rg < 4; ++rg) {
      att[((size_t)(b * SS + i0 + w * 16 + kg * 4 + rg)) * DD + h * DH + nt * 16 + m16] =
          f2bf(O[nt][rg] * linv[rg]);
    }
  }
}

// ---------------------------------------------------------------------------
// LayerNorm over y = ypre + x.
// ---------------------------------------------------------------------------
__global__ __launch_bounds__(256) void ln_kernel(const float* __restrict__ ypre,
                                                 const float* __restrict__ x,
                                                 const float* __restrict__ gamma,
                                                 const float* __restrict__ beta,
                                                 float* __restrict__ out) {
  const int row = blockIdx.x;
  const int t = threadIdx.x;
  const int lane = t & 63, w = t >> 6;
  const float* yr = ypre + (size_t)row * DD;
  const float* xr = x + (size_t)row * DD;

  float4 yv = *(const float4*)(yr + t * 4);
  float4 xv = *(const float4*)(xr + t * 4);
  float v0 = yv.x + xv.x, v1 = yv.y + xv.y, v2 = yv.z + xv.z, v3 = yv.w + xv.w;

  float s = v0 + v1 + v2 + v3;
  float ss = v0 * v0 + v1 * v1 + v2 * v2 + v3 * v3;
  __shared__ float rs[4], rss[4];
#pragma unroll
  for (int off = 32; off; off >>= 1) {
    s += __shfl_xor(s, off);
    ss += __shfl_xor(ss, off);
  }
  if (!lane) { rs[w] = s; rss[w] = ss; }
  __syncthreads();
  s = rs[0] + rs[1] + rs[2] + rs[3];
  ss = rss[0] + rss[1] + rss[2] + rss[3];
  const float mu = s * (1.f / DD);
  const float var = ss * (1.f / DD) - mu * mu;
  const float rstd = rsqrtf(var + 1e-5f);

  float4 g = *(const float4*)(gamma + t * 4);
  float4 be = *(const float4*)(beta + t * 4);
  float4 o;
  o.x = (v0 - mu) * rstd * g.x + be.x;
  o.y = (v1 - mu) * rstd * g.y + be.y;
  o.z = (v2 - mu) * rstd * g.z + be.z;
  o.w = (v3 - mu) * rstd * g.w + be.w;
  *(float4*)(out + (size_t)row * DD + t * 4) = o;
}

// ---------------------------------------------------------------------------
extern "C" void kernel_launch(void* const* d_in, const int* in_sizes, int n_in,
                              void* d_out, int out_size, void* d_ws, size_t ws_size,
                              hipStream_t stream) {
  const float* x = (const float*)d_in[0];
  const float* mem = (const float*)d_in[1];
  const float* R = (const float*)d_in[2];
  const float* u = (const float*)d_in[3];
  const float* tv = (const float*)d_in[4];
  const float* Wq = (const float*)d_in[5];
  const float* Wk = (const float*)d_in[6];
  const float* Wv = (const float*)d_in[7];
  const float* Wr = (const float*)d_in[8];
  const float* Wo = (const float*)d_in[9];
  const float* gamma = (const float*)d_in[10];
  const float* beta = (const float*)d_in[11];
  float* out = (float*)d_out;

  // ws layout (ushort units, 1M = 1<<20):
  ushort* hb = (ushort*)d_ws;                       // 8M  concat(mem,x) bf16; reused as vt
  ushort* Rb = hb + (8u << 20);                     // 1M
  ushort* Wqb = Rb + (1u << 20);                    // 1M
  ushort* Wkb = Wqb + (1u << 20);                   // 1M
  ushort* Wvb = Wkb + (1u << 20);                   // 1M
  ushort* Wrb = Wvb + (1u << 20);                   // 1M
  ushort* Wob = Wrb + (1u << 20);                   // 1M
  ushort* qu_b = Wob + (1u << 20);                  // 4M  (att aliases)
  ushort* qt_b = qu_b + (4u << 20);                 // 4M
  ushort* kb = qt_b + (4u << 20);                   // 8M  (ypre fp32 aliases)
  ushort* vb = kb + (8u << 20);                     // 8M
  ushort* rb = vb + (8u << 20);                     // 1M
  ushort* att = qu_b;
  ushort* vt = hb;   // hb dead after projections
  float* ypre = (float*)kb;

  dim3 blk(256);

  // fused casts (14M elems / 8 / 256 = 7168 blocks)
  cast_all<<<dim3(7168), blk, 0, stream>>>(mem, x, R, Wq, Wk, Wv, Wr, Wo,
                                           hb, Rb, Wqb, Wkb, Wvb, Wrb, Wob);

  // fused q/k/v/r projections (one launch, 1344 blocks)
  gemm_qkvr<<<dim3(1344), blk, 0, stream>>>(hb, Rb, Wqb, Wkb, Wvb, Wrb,
                                            qu_b, qt_b, kb, vb, rb, u, tv);

  // V transpose into vt (= hb region, dead now)
  transp_v<<<dim3(TT / 64, BB * HH), blk, 0, stream>>>(vb, vt);

  attn_mfma<<<dim3(BB * HH, SS / 64), blk, 0, stream>>>(qu_b, qt_b, kb, vt, rb, att);

  gemm_wo<<<dim3(8, 32), blk, 0, stream>>>(att, Wob, ypre);

  ln_kernel<<<dim3(BB * SS), blk, 0, stream>>>(ypre, x, gamma, beta, out);
}

// Round 7
// 195.213 us; speedup vs baseline: 23.1915x; 1.3508x over previous
//
#include <hip/hip_runtime.h>
#include <math.h>

#define BB 8
#define SS 512
#define MM 512
#define TT 1024
#define DD 1024
#define HH 16
#define DH 64

typedef __attribute__((ext_vector_type(8))) short bf16x8;
typedef __attribute__((ext_vector_type(4))) float f32x4;

#define SCL2E 0.1803368801111f  /* 0.125 * log2(e) */
#define DTHR 11.5f              /* defer-max threshold in log2 units */

__device__ __forceinline__ ushort f2bf(float f) {
  union { float f; unsigned u; } x; x.f = f;
  unsigned r = x.u + 0x7fffu + ((x.u >> 16) & 1u);
  return (ushort)(r >> 16);
}

__device__ __forceinline__ void stage16(void* lds, const void* g) {
  __builtin_amdgcn_global_load_lds((const __attribute__((address_space(1))) void*)g,
                                   (__attribute__((address_space(3))) void*)lds, 16, 0, 0);
}

template <int C>
__device__ __forceinline__ float dppf(float x) {
  return __builtin_bit_cast(float,
      __builtin_amdgcn_update_dpp(0, __builtin_bit_cast(int, x), C, 0xF, 0xF, true));
}
__device__ __forceinline__ float redmax16(float x) {
  x = fmaxf(x, dppf<0xB1>(x));
  x = fmaxf(x, dppf<0x4E>(x));
  x = fmaxf(x, dppf<0x141>(x));
  x = fmaxf(x, dppf<0x140>(x));
  return x;
}
__device__ __forceinline__ float redsum16(float x) {
  x += dppf<0xB1>(x);
  x += dppf<0x4E>(x);
  x += dppf<0x141>(x);
  x += dppf<0x140>(x);
  return x;
}
__device__ __forceinline__ float bperm_f(int byteaddr, float v) {
  return __builtin_bit_cast(float,
      __builtin_amdgcn_ds_bpermute(byteaddr, __builtin_bit_cast(int, v)));
}

// ---------------------------------------------------------------------------
// Fused fp32->bf16 casts (segment decode per block range).
// ---------------------------------------------------------------------------
__global__ __launch_bounds__(256) void cast_all(
    const float* __restrict__ mem, const float* __restrict__ x,
    const float* __restrict__ R, const float* __restrict__ Wq,
    const float* __restrict__ Wk, const float* __restrict__ Wv,
    const float* __restrict__ Wr, const float* __restrict__ Wo,
    ushort* __restrict__ hb, ushort* __restrict__ Rb, ushort* __restrict__ Wqb,
    ushort* __restrict__ Wkb, ushort* __restrict__ Wvb, ushort* __restrict__ Wrb,
    ushort* __restrict__ Wob) {
  const int M1 = 1 << 20;
  int i = (blockIdx.x * 256 + threadIdx.x) * 8;
  const float* src;
  ushort* dst;
  if (i < 4 * M1) {
    src = mem + i;
    dst = hb + (size_t)i + (size_t)(i >> 19) * 524288;
  } else if (i < 8 * M1) {
    int j = i - 4 * M1;
    src = x + j;
    dst = hb + (size_t)j + (size_t)(j >> 19) * 524288 + 524288;
  } else if (i < 9 * M1) {
    src = R + (i - 8 * M1);  dst = Rb + (i - 8 * M1);
  } else if (i < 10 * M1) {
    src = Wq + (i - 9 * M1); dst = Wqb + (i - 9 * M1);
  } else if (i < 11 * M1) {
    src = Wk + (i - 10 * M1); dst = Wkb + (i - 10 * M1);
  } else if (i < 12 * M1) {
    src = Wv + (i - 11 * M1); dst = Wvb + (i - 11 * M1);
  } else if (i < 13 * M1) {
    src = Wr + (i - 12 * M1); dst = Wrb + (i - 12 * M1);
  } else {
    src = Wo + (i - 13 * M1); dst = Wob + (i - 13 * M1);
  }
  float4 a = *(const float4*)(src);
  float4 c = *(const float4*)(src + 4);
  union { bf16x8 v; ushort u[8]; } pk;
  pk.u[0] = f2bf(a.x); pk.u[1] = f2bf(a.y); pk.u[2] = f2bf(a.z); pk.u[3] = f2bf(a.w);
  pk.u[4] = f2bf(c.x); pk.u[5] = f2bf(c.y); pk.u[6] = f2bf(c.z); pk.u[7] = f2bf(c.w);
  *(bf16x8*)(void*)dst = pk.v;
}

// ---------------------------------------------------------------------------
// Fused q/k/v/r projection GEMM (m97 structure). 1344 blocks.
// bid<256: q (dual +u/+t). <768: k. <1280: v (TRANSPOSED store to vt). else r.
// vt[b*1024 + col][t] : col = h*64+d; 4 consecutive t per ushort4 store.
// ---------------------------------------------------------------------------
__global__ __launch_bounds__(256) void gemm_qkvr(
    const ushort* __restrict__ hb, const ushort* __restrict__ Rbuf,
    const ushort* __restrict__ Wqb, const ushort* __restrict__ Wkb,
    const ushort* __restrict__ Wvb, const ushort* __restrict__ Wrb,
    ushort* __restrict__ qub, ushort* __restrict__ qtb,
    ushort* __restrict__ kbo, ushort* __restrict__ vtb, ushort* __restrict__ rbo,
    const float* __restrict__ uvec, const float* __restrict__ tvec) {
  __shared__ ushort As[128 * 32];
  __shared__ ushort Bs[128 * 32];
  const int bid = blockIdx.x;
  const ushort* A;
  const ushort* W;
  ushort* C0 = nullptr;
  ushort* C1 = nullptr;
  bool dual = false, qslice = false, vmode = false;
  int mt, nx;
  if (bid < 256) {
    int r = bid; mt = r >> 3; nx = r & 7;
    A = hb; W = Wqb; C0 = qub; C1 = qtb; dual = true; qslice = true;
  } else if (bid < 768) {
    int r = bid - 256; mt = r >> 3; nx = r & 7;
    A = hb; W = Wkb; C0 = kbo;
  } else if (bid < 1280) {
    int r = bid - 768; mt = r >> 3; nx = r & 7;
    A = hb; W = Wvb; C0 = vtb; vmode = true;
  } else {
    int r = bid - 1280; mt = r >> 3; nx = r & 7;
    A = Rbuf; W = Wrb; C0 = rbo;
  }
  const int m0 = mt * 128, n0 = nx * 128;

  const int t = threadIdx.x;
  const int w = t >> 6, l = t & 63;
  const int m16 = l & 15, kg = l >> 4;
  const int wr = w >> 1, wc = w & 1;

  const int c0 = t, c1 = t + 256;
  const ushort* asrc0;
  const ushort* asrc1;
  {
    int gm0 = m0 + (c0 >> 2), gm1 = m0 + (c1 >> 2);
    if (qslice) {
      asrc0 = A + ((size_t)((gm0 >> 9) * TT + MM + (gm0 & 511))) * DD + (c0 & 3) * 8;
      asrc1 = A + ((size_t)((gm1 >> 9) * TT + MM + (gm1 & 511))) * DD + (c1 & 3) * 8;
    } else {
      asrc0 = A + (size_t)gm0 * DD + (c0 & 3) * 8;
      asrc1 = A + (size_t)gm1 * DD + (c1 & 3) * 8;
    }
  }
  const ushort* bsrc0 = W + (size_t)(n0 + (c0 >> 2)) * DD + (c0 & 3) * 8;
  const ushort* bsrc1 = W + (size_t)(n0 + (c1 >> 2)) * DD + (c1 & 3) * 8;
  ushort* adst0 = As + c0 * 8;
  ushort* adst1 = As + c1 * 8;
  ushort* bdst0 = Bs + c0 * 8;
  ushort* bdst1 = Bs + c1 * 8;

  f32x4 acc[4][4];
#pragma unroll
  for (int mi = 0; mi < 4; ++mi)
#pragma unroll
    for (int ni = 0; ni < 4; ++ni) acc[mi][ni] = (f32x4){0.f, 0.f, 0.f, 0.f};

  for (int k0 = 0; k0 < DD; k0 += 32) {
    stage16(adst0, asrc0 + k0);
    stage16(adst1, asrc1 + k0);
    stage16(bdst0, bsrc0 + k0);
    stage16(bdst1, bsrc1 + k0);
    __syncthreads();
    bf16x8 af[4], bfr[4];
#pragma unroll
    for (int mi = 0; mi < 4; ++mi)
      af[mi] = *(const bf16x8*)(const void*)&As[(wr * 64 + mi * 16 + m16) * 32 + kg * 8];
#pragma unroll
    for (int ni = 0; ni < 4; ++ni)
      bfr[ni] = *(const bf16x8*)(const void*)&Bs[(wc * 64 + ni * 16 + m16) * 32 + kg * 8];
#pragma unroll
    for (int mi = 0; mi < 4; ++mi)
#pragma unroll
      for (int ni = 0; ni < 4; ++ni)
        acc[mi][ni] = __builtin_amdgcn_mfma_f32_16x16x32_bf16(af[mi], bfr[ni], acc[mi][ni], 0, 0, 0);
    __syncthreads();
  }

  const int rbase = m0 + wr * 64 + kg * 4;
  const int cbase = n0 + wc * 64 + m16;
  if (vmode) {
    // transposed store: vt[(b*1024 + col)][t], 4 consecutive t (=rg) per store
    const int bb = m0 >> 10;
    const int tt0 = (m0 & 1023) + wr * 64 + kg * 4;
#pragma unroll
    for (int mi = 0; mi < 4; ++mi)
#pragma unroll
      for (int ni = 0; ni < 4; ++ni) {
        ushort4 o;
        o.x = f2bf(acc[mi][ni][0]); o.y = f2bf(acc[mi][ni][1]);
        o.z = f2bf(acc[mi][ni][2]); o.w = f2bf(acc[mi][ni][3]);
        *(ushort4*)(C0 + ((size_t)(bb * 1024 + cbase + ni * 16) << 10) + tt0 + mi * 16) = o;
      }
  } else if (dual) {
    float uv[4], tv[4];
#pragma unroll
    for (int ni = 0; ni < 4; ++ni) { uv[ni] = uvec[cbase + ni * 16]; tv[ni] = tvec[cbase + ni * 16]; }
#pragma unroll
    for (int mi = 0; mi < 4; ++mi)
#pragma unroll
      for (int ni = 0; ni < 4; ++ni)
#pragma unroll
        for (int rg = 0; rg < 4; ++rg) {
          size_t idx = (size_t)(rbase + mi * 16 + rg) * DD + cbase + ni * 16;
          C0[idx] = f2bf(acc[mi][ni][rg] + uv[ni]);
          C1[idx] = f2bf(acc[mi][ni][rg] + tv[ni]);
        }
  } else {
#pragma unroll
    for (int mi = 0; mi < 4; ++mi)
#pragma unroll
      for (int ni = 0; ni < 4; ++ni)
#pragma unroll
        for (int rg = 0; rg < 4; ++rg)
          C0[(size_t)(rbase + mi * 16 + rg) * DD + cbase + ni * 16] = f2bf(acc[mi][ni][rg]);
  }
}

// ---------------------------------------------------------------------------
// MFMA GEMM for Wo: fp32 out (m97 structure).
// ---------------------------------------------------------------------------
__global__ __launch_bounds__(256) void gemm_wo(const ushort* __restrict__ A,
                                               const ushort* __restrict__ W,
                                               float* __restrict__ Cf) {
  __shared__ ushort As[128 * 32];
  __shared__ ushort Bs[128 * 32];
  const int t = threadIdx.x;
  const int w = t >> 6, l = t & 63;
  const int m16 = l & 15, kg = l >> 4;
  const int m0 = blockIdx.y * 128, n0 = blockIdx.x * 128;
  const int wr = w >> 1, wc = w & 1;

  const int c0 = t, c1 = t + 256;
  const ushort* asrc0 = A + (size_t)(m0 + (c0 >> 2)) * DD + (c0 & 3) * 8;
  const ushort* asrc1 = A + (size_t)(m0 + (c1 >> 2)) * DD + (c1 & 3) * 8;
  const ushort* bsrc0 = W + (size_t)(n0 + (c0 >> 2)) * DD + (c0 & 3) * 8;
  const ushort* bsrc1 = W + (size_t)(n0 + (c1 >> 2)) * DD + (c1 & 3) * 8;
  ushort* adst0 = As + c0 * 8;
  ushort* adst1 = As + c1 * 8;
  ushort* bdst0 = Bs + c0 * 8;
  ushort* bdst1 = Bs + c1 * 8;

  f32x4 acc[4][4];
#pragma unroll
  for (int mi = 0; mi < 4; ++mi)
#pragma unroll
    for (int ni = 0; ni < 4; ++ni) acc[mi][ni] = (f32x4){0.f, 0.f, 0.f, 0.f};

  for (int k0 = 0; k0 < DD; k0 += 32) {
    stage16(adst0, asrc0 + k0);
    stage16(adst1, asrc1 + k0);
    stage16(bdst0, bsrc0 + k0);
    stage16(bdst1, bsrc1 + k0);
    __syncthreads();
    bf16x8 af[4], bfr[4];
#pragma unroll
    for (int mi = 0; mi < 4; ++mi)
      af[mi] = *(const bf16x8*)(const void*)&As[(wr * 64 + mi * 16 + m16) * 32 + kg * 8];
#pragma unroll
    for (int ni = 0; ni < 4; ++ni)
      bfr[ni] = *(const bf16x8*)(const void*)&Bs[(wc * 64 + ni * 16 + m16) * 32 + kg * 8];
#pragma unroll
    for (int mi = 0; mi < 4; ++mi)
#pragma unroll
      for (int ni = 0; ni < 4; ++ni)
        acc[mi][ni] = __builtin_amdgcn_mfma_f32_16x16x32_bf16(af[mi], bfr[ni], acc[mi][ni], 0, 0, 0);
    __syncthreads();
  }

  const int rbase = m0 + wr * 64 + kg * 4;
  const int cbase = n0 + wc * 64 + m16;
#pragma unroll
  for (int mi = 0; mi < 4; ++mi)
#pragma unroll
    for (int ni = 0; ni < 4; ++ni)
#pragma unroll
      for (int rg = 0; rg < 4; ++rg)
        Cf[(size_t)(rbase + mi * 16 + rg) * DD + cbase + ni * 16] = acc[mi][ni][rg];
}

// ---------------------------------------------------------------------------
// MFMA flash attention. 4 waves/block; q rows [i0+16w, i0+16w+16) per wave.
// K double-buffered LDS (prefetched mid-compute); V single-buffered (staged at
// iter top); R in a 128-row ring (64 new rows staged/iter). All staging via
// global_load_lds with XOR-swizzled SOURCE (linear LDS dest); reads apply the
// same swizzle (involution). bd gather: ds_bpermute. Reductions: DPP.
// Softmax in log2 domain; mask only on last j-tile (clamped R rows feed only
// masked entries). 2 barriers/iter. Grid 1D, longest blocks dispatched first.
// ---------------------------------------------------------------------------
__global__ __launch_bounds__(256) void attn_mfma(const ushort* __restrict__ qu,
                                                 const ushort* __restrict__ qt,
                                                 const ushort* __restrict__ kb,
                                                 const ushort* __restrict__ vt,
                                                 const ushort* __restrict__ rb,
                                                 ushort* __restrict__ att) {
  const int w = threadIdx.x >> 6;
  const int l = threadIdx.x & 63;
  const int m16 = l & 15;
  const int kg = l >> 4;
  const int bid = blockIdx.x;
  const int it = 7 - (bid >> 7);         // longest (it=7, ntj=16) first
  const int bh = bid & 127;
  const int b = bh >> 4, h = bh & 15;
  const int i0 = it * 64;

  __shared__ ushort Ks[2][4096];       // [j][k] swizzled, dbuf (16 KB)
  __shared__ ushort Vs[4096];          // [d][j] swizzled (8 KB)
  __shared__ ushort Rl[8192];          // ring: 128 rows x 64 cols swizzled (16 KB)
  __shared__ ushort plds[4][16][72];   // per-wave P tile (9.2 KB)

  // Q fragments
  bf16x8 aqu[2], aqt[2];
  {
    const ushort* qrow = qu + ((size_t)(b * SS + i0 + w * 16 + m16)) * DD + h * DH + kg * 8;
    aqu[0] = *(const bf16x8*)(const void*)(qrow);
    aqu[1] = *(const bf16x8*)(const void*)(qrow + 32);
    const ushort* qrow2 = qt + ((size_t)(b * SS + i0 + w * 16 + m16)) * DD + h * DH + kg * 8;
    aqt[0] = *(const bf16x8*)(const void*)(qrow2);
    aqt[1] = *(const bf16x8*)(const void*)(qrow2 + 32);
  }

  // circulant gather lane addressing (verified r5/r6)
  int baddr[4];
  bool bsel[4];
#pragma unroll
  for (int rg = 0; rg < 4; ++rg) {
    const int rw = kg * 4 + rg;
    baddr[rg] = (kg * 16 + ((m16 + 15 - rw) & 15)) << 2;
    bsel[rg] = m16 > rw;
  }

  // staging thread addressing: chunk c -> row c>>3, colchunk c&7 (16B each)
  const int c0 = threadIdx.x, c1 = threadIdx.x + 256;
  const int r0 = c0 >> 3, sc0 = ((c0 & 7) * 8) ^ ((r0 & 7) << 3);
  const int r1 = c1 >> 3, sc1 = ((c1 & 7) * 8) ^ ((r1 & 7) << 3);
  const ushort* kp0 = kb + ((size_t)(b * TT) + r0) * DD + h * DH + sc0;
  const ushort* kp1 = kb + ((size_t)(b * TT) + r1) * DD + h * DH + sc1;
  const ushort* vp0 = vt + ((size_t)(b * 1024 + h * DH + r0)) * 1024 + sc0;
  const ushort* vp1 = vt + ((size_t)(b * 1024 + h * DH + r1)) * 1024 + sc1;

  // R fragment read addressing: p(f) = 496 - i0 - w*16 + m16 + f*16 + j0
  // ring slot = p & 127; ushort addr = slot*64 + cb[ks]; cb = (kg*8+ks*32)^((m16&7)<<3)
  const int cb0 = (kg * 8) ^ ((m16 & 7) << 3);
  const int cb1 = (kg * 8 + 32) ^ ((m16 & 7) << 3);
  int slot64[5];
#pragma unroll
  for (int f = 0; f < 5; ++f)
    slot64[f] = ((496 - i0 - w * 16 + m16 + f * 16) & 127) << 6;

  // ---- prologue: R window(0) = rows [448-i0, 576-i0) (no clamp needed) ----
  {
    const int base0 = 448 - i0;
#pragma unroll
    for (int kk = 0; kk < 4; ++kk) {
      int c = threadIdx.x + kk * 256;
      int ro = c >> 3, cc = c & 7;
      int p = base0 + ro;
      int slot = p & 127;
      stage16(Rl + slot * 64 + cc * 8,
              rb + (size_t)p * DD + h * DH + ((cc * 8) ^ ((ro & 7) << 3)));
    }
  }
  // K(0), V(0)
  stage16(&Ks[0][c0 * 8], kp0);
  stage16(&Ks[0][c1 * 8], kp1);
  stage16(Vs + c0 * 8, vp0);
  stage16(Vs + c1 * 8, vp1);
  kp0 += (size_t)64 * DD; kp1 += (size_t)64 * DD;
  vp0 += 64; vp1 += 64;

  f32x4 O[4];
  float mrow[4], lrow[4];
#pragma unroll
  for (int nt = 0; nt < 4; ++nt) O[nt] = (f32x4){0.f, 0.f, 0.f, 0.f};
#pragma unroll
  for (int rg = 0; rg < 4; ++rg) { mrow[rg] = -1e30f; lrow[rg] = 0.f; }

  const int ntj = it + 9;
  int cur = 0;
  for (int jt = 0; jt < ntj; ++jt) {
    const int j0 = jt * 64;

    // ---- top: stage V(jt) and the 64 incoming R rows (jt>=1) ----
    if (jt > 0) {
      stage16(Vs + c0 * 8, vp0);
      stage16(Vs + c1 * 8, vp1);
      vp0 += 64; vp1 += 64;
      const int pstart = 512 + j0 - i0;
#pragma unroll
      for (int kk = 0; kk < 2; ++kk) {
        int c = threadIdx.x + kk * 256;
        int ro = c >> 3, cc = c & 7;
        int p = pstart + ro;
        int pc = p < 1023 ? p : 1023;  // clamped rows feed masked entries only
        int slot = p & 127;
        stage16(Rl + slot * 64 + cc * 8,
                rb + (size_t)pc * DD + h * DH + ((cc * 8) ^ ((ro & 7) << 3)));
      }
    }
    __syncthreads();  // barrier1: drains V/R (and prologue at jt=0, K prefetch from prev iter)

    // ---- ac = qu . K^T (swizzled LDS reads from Ks[cur]) ----
    const ushort* kbase = &Ks[cur][0];
    f32x4 ac[4];
#pragma unroll
    for (int nt = 0; nt < 4; ++nt) {
      ac[nt] = (f32x4){0.f, 0.f, 0.f, 0.f};
      const int row = nt * 16 + m16;
#pragma unroll
      for (int ks = 0; ks < 2; ++ks) {
        bf16x8 bk = *(const bf16x8*)(const void*)(kbase + row * 64 + (ks == 0 ? cb0 : cb1));
        ac[nt] = __builtin_amdgcn_mfma_f32_16x16x32_bf16(aqu[ks], bk, ac[nt], 0, 0, 0);
      }
    }

    // ---- prefetch K(jt+1) mid-compute (drained at barrier2) ----
    if (jt + 1 < ntj) {
      stage16(&Ks[cur ^ 1][c0 * 8], kp0);
      stage16(&Ks[cur ^ 1][c1 * 8], kp1);
      kp0 += (size_t)64 * DD; kp1 += (size_t)64 * DD;
    }

    // ---- bd strip 16x80 (R frags from ring LDS) ----
    f32x4 bd[5];
#pragma unroll
    for (int f = 0; f < 5; ++f) {
      f32x4 z = (f32x4){0.f, 0.f, 0.f, 0.f};
      bf16x8 b0 = *(const bf16x8*)(const void*)(Rl + slot64[f] + cb0);
      z = __builtin_amdgcn_mfma_f32_16x16x32_bf16(aqt[0], b0, z, 0, 0, 0);
      bf16x8 b1 = *(const bf16x8*)(const void*)(Rl + slot64[f] + cb1);
      bd[f] = __builtin_amdgcn_mfma_f32_16x16x32_bf16(aqt[1], b1, z, 0, 0, 0);
    }
#pragma unroll
    for (int f = 0; f < 5; ++f) slot64[f] = (slot64[f] + 4096) & 8191;

    // ---- gather + scale (log2 domain) ----
    float sca[4][4];
#pragma unroll
    for (int rg = 0; rg < 4; ++rg) {
      float rr[5];
#pragma unroll
      for (int f = 0; f < 5; ++f) rr[f] = bperm_f(baddr[rg], bd[f][rg]);
#pragma unroll
      for (int nt = 0; nt < 4; ++nt) {
        float bdv = bsel[rg] ? rr[nt + 1] : rr[nt];
        sca[nt][rg] = (ac[nt][rg] + bdv) * SCL2E;
      }
    }
    if (jt == ntj - 1) {
#pragma unroll
      for (int rg = 0; rg < 4; ++rg) {
        const int jmax = i0 + w * 16 + kg * 4 + rg + MM;
#pragma unroll
        for (int nt = 0; nt < 4; ++nt)
          sca[nt][rg] = (j0 + nt * 16 + m16 <= jmax) ? sca[nt][rg] : -1e30f;
      }
    }

    // ---- rowmax (DPP) + defer-max rescale ----
    float pmax[4];
#pragma unroll
    for (int rg = 0; rg < 4; ++rg) {
      float pm = fmaxf(fmaxf(sca[0][rg], sca[1][rg]), fmaxf(sca[2][rg], sca[3][rg]));
      pmax[rg] = redmax16(pm);
    }
    bool grow = false;
#pragma unroll
    for (int rg = 0; rg < 4; ++rg) grow = grow || (pmax[rg] > mrow[rg] + DTHR);
    if (__any(grow)) {
#pragma unroll
      for (int rg = 0; rg < 4; ++rg) {
        float mnew = fmaxf(mrow[rg], pmax[rg]);
        float scale = __builtin_amdgcn_exp2f(mrow[rg] - mnew);
        mrow[rg] = mnew;
        lrow[rg] *= scale;
#pragma unroll
        for (int nt = 0; nt < 4; ++nt) O[nt][rg] *= scale;
      }
    }

    // ---- p = exp2(s-m), row-sum (DPP), P -> plds ----
#pragma unroll
    for (int rg = 0; rg < 4; ++rg) {
      float ps = 0.f;
#pragma unroll
      for (int nt = 0; nt < 4; ++nt) {
        float p = __builtin_amdgcn_exp2f(sca[nt][rg] - mrow[rg]);
        ps += p;
        plds[w][kg * 4 + rg][nt * 16 + m16] = f2bf(p);
      }
      lrow[rg] += redsum16(ps);
    }

    // ---- PV: O += P . V (V frags from swizzled LDS) ----
#pragma unroll
    for (int ks = 0; ks < 2; ++ks) {
      bf16x8 pa = *(const bf16x8*)(const void*)&plds[w][m16][kg * 8 + ks * 32];
#pragma unroll
      for (int nt = 0; nt < 4; ++nt) {
        bf16x8 vf = *(const bf16x8*)(const void*)(Vs + (nt * 16 + m16) * 64 + (ks == 0 ? cb0 : cb1));
        O[nt] = __builtin_amdgcn_mfma_f32_16x16x32_bf16(pa, vf, O[nt], 0, 0, 0);
      }
    }

    __syncthreads();  // barrier2: drains K prefetch; protects Vs/Rl/Ks[cur] reuse
    cur ^= 1;
  }

  // ---- epilogue ----
  float linv[4];
#pragma unroll
  for (int rg = 0; rg < 4; ++rg) linv[rg] = 1.f / lrow[rg];
#pragma unroll
  for (int nt = 0; nt < 4; ++nt) {
#pragma unroll
    for (int rg = 0; rg < 4; ++rg) {
      att[((size_t)(b * SS + i0 + w * 16 + kg * 4 + rg)) * DD + h * DH + nt * 16 + m16] =
          f2bf(O[nt][rg] * linv[rg]);
    }
  }
}

// ---------------------------------------------------------------------------
// LayerNorm over y = ypre + x.
// ---------------------------------------------------------------------------
__global__ __launch_bounds__(256) void ln_kernel(const float* __restrict__ ypre,
                                                 const float* __restrict__ x,
                                                 const float* __restrict__ gamma,
                                                 const float* __restrict__ beta,
                                                 float* __restrict__ out) {
  const int row = blockIdx.x;
  const int t = threadIdx.x;
  const int lane = t & 63, w = t >> 6;
  const float* yr = ypre + (size_t)row * DD;
  const float* xr = x + (size_t)row * DD;

  float4 yv = *(const float4*)(yr + t * 4);
  float4 xv = *(const float4*)(xr + t * 4);
  float v0 = yv.x + xv.x, v1 = yv.y + xv.y, v2 = yv.z + xv.z, v3 = yv.w + xv.w;

  float s = v0 + v1 + v2 + v3;
  float ss = v0 * v0 + v1 * v1 + v2 * v2 + v3 * v3;
  __shared__ float rs[4], rss[4];
#pragma unroll
  for (int off = 32; off; off >>= 1) {
    s += __shfl_xor(s, off);
    ss += __shfl_xor(ss, off);
  }
  if (!lane) { rs[w] = s; rss[w] = ss; }
  __syncthreads();
  s = rs[0] + rs[1] + rs[2] + rs[3];
  ss = rss[0] + rss[1] + rss[2] + rss[3];
  const float mu = s * (1.f / DD);
  const float var = ss * (1.f / DD) - mu * mu;
  const float rstd = rsqrtf(var + 1e-5f);

  float4 g = *(const float4*)(gamma + t * 4);
  float4 be = *(const float4*)(beta + t * 4);
  float4 o;
  o.x = (v0 - mu) * rstd * g.x + be.x;
  o.y = (v1 - mu) * rstd * g.y + be.y;
  o.z = (v2 - mu) * rstd * g.z + be.z;
  o.w = (v3 - mu) * rstd * g.w + be.w;
  *(float4*)(out + (size_t)row * DD + t * 4) = o;
}

// ---------------------------------------------------------------------------
extern "C" void kernel_launch(void* const* d_in, const int* in_sizes, int n_in,
                              void* d_out, int out_size, void* d_ws, size_t ws_size,
                              hipStream_t stream) {
  const float* x = (const float*)d_in[0];
  const float* mem = (const float*)d_in[1];
  const float* R = (const float*)d_in[2];
  const float* u = (const float*)d_in[3];
  const float* tv = (const float*)d_in[4];
  const float* Wq = (const float*)d_in[5];
  const float* Wk = (const float*)d_in[6];
  const float* Wv = (const float*)d_in[7];
  const float* Wr = (const float*)d_in[8];
  const float* Wo = (const float*)d_in[9];
  const float* gamma = (const float*)d_in[10];
  const float* beta = (const float*)d_in[11];
  float* out = (float*)d_out;

  // ws layout (ushort units, 1M = 1<<20):
  ushort* hb = (ushort*)d_ws;                       // 8M  concat(mem,x) bf16
  ushort* Rb = hb + (8u << 20);                     // 1M
  ushort* Wqb = Rb + (1u << 20);                    // 1M
  ushort* Wkb = Wqb + (1u << 20);                   // 1M
  ushort* Wvb = Wkb + (1u << 20);                   // 1M
  ushort* Wrb = Wvb + (1u << 20);                   // 1M
  ushort* Wob = Wrb + (1u << 20);                   // 1M
  ushort* qu_b = Wob + (1u << 20);                  // 4M  (att aliases)
  ushort* qt_b = qu_b + (4u << 20);                 // 4M
  ushort* kb = qt_b + (4u << 20);                   // 8M  (ypre fp32 aliases)
  ushort* vt = kb + (8u << 20);                     // 8M  V stored TRANSPOSED
  ushort* rb = vt + (8u << 20);                     // 1M
  ushort* att = qu_b;
  float* ypre = (float*)kb;

  dim3 blk(256);

  // fused casts (14M elems / 8 / 256 = 7168 blocks)
  cast_all<<<dim3(7168), blk, 0, stream>>>(mem, x, R, Wq, Wk, Wv, Wr, Wo,
                                           hb, Rb, Wqb, Wkb, Wvb, Wrb, Wob);

  // fused q/k/v/r projections (V written transposed into vt)
  gemm_qkvr<<<dim3(1344), blk, 0, stream>>>(hb, Rb, Wqb, Wkb, Wvb, Wrb,
                                            qu_b, qt_b, kb, vt, rb, u, tv);

  // attention: 1D grid, longest blocks first
  attn_mfma<<<dim3(BB * HH * 8), blk, 0, stream>>>(qu_b, qt_b, kb, vt, rb, att);

  gemm_wo<<<dim3(8, 32), blk, 0, stream>>>(att, Wob, ypre);

  ln_kernel<<<dim3(BB * SS), blk, 0, stream>>>(ypre, x, gamma, beta, out);
}